// Round 1
// baseline (1175.879 us; speedup 1.0000x reference)
//
#include <hip/hip_runtime.h>
#include <math.h>

typedef __bf16 bf16_t;
typedef __attribute__((ext_vector_type(8))) __bf16 bf16x8;
typedef __attribute__((ext_vector_type(4))) float f32x4;

#define D_MODEL   2048
#define L_SEQ     2048
#define BATCH     2
#define NTOK      4096      // BATCH * L_SEQ
#define N_HEADS   32
#define D_STATE   64
#define HEADDIM   64
#define D_INNER   2048
#define CONV_DIM  6144      // d_inner + 2*H*N
#define D_IN_PROJ 8224      // 2*d_inner + 2*H*N + H
#define INTER     5504
#define QCHUNK    128       // scan chunk length
#define KCHUNKS   16        // L_SEQ / QCHUNK

// ---------------------------------------------------------------------------
// async global->LDS (width 16B). HW dest = wave-uniform base + lane*16; our
// LDS layouts are linear in tid*16 so per-lane pointers match HW placement.
__device__ __forceinline__ void gld_lds16(const void* g, void* l) {
    __builtin_amdgcn_global_load_lds(
        (const __attribute__((address_space(1))) unsigned int*)g,
        (__attribute__((address_space(3))) unsigned int*)l, 16, 0, 0);
}

// ---------------------------------------------------------------------------
// f32 -> bf16 convert, 8 elems/thread
__global__ __launch_bounds__(256) void cvt_kernel(
    const float* __restrict__ s, bf16_t* __restrict__ d, int n8)
{
    int i = blockIdx.x * 256 + threadIdx.x;
    if (i >= n8) return;
    const float4* s4 = (const float4*)s;
    float4 a = s4[2 * i], b = s4[2 * i + 1];
    bf16x8 r;
    r[0] = (bf16_t)a.x; r[1] = (bf16_t)a.y; r[2] = (bf16_t)a.z; r[3] = (bf16_t)a.w;
    r[4] = (bf16_t)b.x; r[5] = (bf16_t)b.y; r[6] = (bf16_t)b.z; r[7] = (bf16_t)b.w;
    ((bf16x8*)d)[i] = r;
}

// ---------------------------------------------------------------------------
// RMSNorm: one block per token row; f32 in, bf16 out.
__global__ __launch_bounds__(256) void rmsnorm_kernel(
    const float* __restrict__ x, const float* __restrict__ w,
    const float* __restrict__ mask, bf16_t* __restrict__ out)
{
    __shared__ float red[4];
    __shared__ float sinv;
    int row = blockIdx.x;
    const float* xr = x + (size_t)row * D_MODEL;
    float xv[8];
    float ss = 0.f;
#pragma unroll
    for (int i = 0; i < 8; ++i) {
        float v = xr[threadIdx.x + 256 * i];
        xv[i] = v;
        ss += v * v;
    }
    for (int off = 32; off >= 1; off >>= 1) ss += __shfl_down(ss, off, 64);
    int lane = threadIdx.x & 63, wv = threadIdx.x >> 6;
    if (lane == 0) red[wv] = ss;
    __syncthreads();
    if (threadIdx.x == 0) {
        float t = red[0] + red[1] + red[2] + red[3];
        sinv = rsqrtf(t / (float)D_MODEL + 1e-6f);
    }
    __syncthreads();
    float s = sinv;
    float m = mask ? mask[row] : 1.f;
    bf16_t* orow = out + (size_t)row * D_MODEL;
#pragma unroll
    for (int i = 0; i < 8; ++i) {
        int c = threadIdx.x + 256 * i;
        orow[c] = (bf16_t)(xv[i] * s * w[c] * m);
    }
}

// ---------------------------------------------------------------------------
// GEMM (m97 structure, 128x128 tile, BK=32): O[M,N] = X[M,K] @ W[N,K]^T
// (+ optional f32 residual R). Kept for small-N GEMMs (out_proj, down,
// in_proj A_log strip) where the 256^2 kernel would underfill the GPU.
template <bool RES, typename OT>
__global__ __launch_bounds__(256) void gemm_bt(
    const bf16_t* __restrict__ X, const bf16_t* __restrict__ W,
    const float* __restrict__ R, OT* __restrict__ O,
    int N, int K, int ldo)
{
    __shared__ __attribute__((aligned(16))) bf16_t As[128 * 32];
    __shared__ __attribute__((aligned(16))) bf16_t Bs[128 * 32];

    int tid = threadIdx.x;
    int m0 = blockIdx.y * 128;
    int n0 = blockIdx.x * 128;

    f32x4 acc[4][4] = {};

    int lane = tid & 63;
    int wv = tid >> 6;
    int wm = (wv >> 1) * 64, wn = (wv & 1) * 64;
    int lm = lane & 15, lq = lane >> 4;

    int srow = tid >> 2;            // 0..63
    int scol = (tid & 3) * 8;       // element col 0/8/16/24
    const bf16_t* Xp0 = X + (size_t)(m0 + srow) * K + scol;
    const bf16_t* Xp1 = X + (size_t)(m0 + 64 + srow) * K + scol;
    int wr0 = n0 + srow;      if (wr0 > N - 1) wr0 = N - 1;  // clamp OOB rows
    int wr1 = n0 + 64 + srow; if (wr1 > N - 1) wr1 = N - 1;
    const bf16_t* Wp0 = W + (size_t)wr0 * K + scol;
    const bf16_t* Wp1 = W + (size_t)wr1 * K + scol;
    bf16_t* lA0 = &As[tid * 8];
    bf16_t* lA1 = &As[2048 + tid * 8];
    bf16_t* lB0 = &Bs[tid * 8];
    bf16_t* lB1 = &Bs[2048 + tid * 8];

    for (int k0 = 0; k0 < K; k0 += 32) {
        __syncthreads();                 // prev iter's LDS reads done
        gld_lds16(Xp0 + k0, lA0);
        gld_lds16(Xp1 + k0, lA1);
        gld_lds16(Wp0 + k0, lB0);
        gld_lds16(Wp1 + k0, lB1);
        __syncthreads();                 // compiler drains vmcnt before barrier

        bf16x8 a[4], b[4];
#pragma unroll
        for (int i = 0; i < 4; ++i)
            a[i] = *(const bf16x8*)&As[(wm + i * 16 + lm) * 32 + lq * 8];
#pragma unroll
        for (int i = 0; i < 4; ++i)
            b[i] = *(const bf16x8*)&Bs[(wn + i * 16 + lm) * 32 + lq * 8];
#pragma unroll
        for (int mi = 0; mi < 4; ++mi)
#pragma unroll
            for (int ni = 0; ni < 4; ++ni)
                acc[mi][ni] = __builtin_amdgcn_mfma_f32_16x16x32_bf16(
                    a[mi], b[ni], acc[mi][ni], 0, 0, 0);
    }

    // epilogue: C/D layout col=lane&15, row=(lane>>4)*4+reg  [verified m89/m91]
#pragma unroll
    for (int mi = 0; mi < 4; ++mi)
#pragma unroll
        for (int ni = 0; ni < 4; ++ni) {
            int n = n0 + wn + ni * 16 + lm;
            if (n >= N) continue;
            int mbase = m0 + wm + mi * 16 + lq * 4;
#pragma unroll
            for (int r = 0; r < 4; ++r) {
                size_t off = (size_t)(mbase + r) * ldo + n;
                float v = acc[mi][ni][r];
                if (RES) v += R[off];
                O[off] = (OT)v;
            }
        }
}

// ---------------------------------------------------------------------------
// 256x256 8-phase GEMM (T1 XCD swizzle + T2 st_16x32 LDS swizzle + T3/T4
// counted-vmcnt 8-phase + T5 setprio):  O[M,N] = X[M,K] @ W[N,K]^T.
// Requirements: M == gridDim.y*256, K % 128 == 0, N <= gridDim.x*256
// (OOB W rows clamped, OOB cols not stored). 512 threads = 8 waves (2Mx4N),
// per-wave 128x64 output (acc[8][4]); LDS 128 KiB = 2 dbuf slots of
// {A: 2x(128x64), B: 2x(128x64)} bf16.
//
// LDS layout per 16 KiB half-tile: 16-row x 32-col subtiles stored
// contiguously (1024 B), XOR-swizzled: byte ^= ((byte>>9)&1)<<5, i.e. rows
// with bit3 set swap 16-elem column halves -> ds_read_b128 conflicts drop
// 16-way -> ~4-way. global_load_lds writes linearly (tid*16); the swizzle is
// applied by pre-permuting the per-lane GLOBAL source address (both-sides
// rule, m104/m201).
//
// Schedule per iteration (2 K-tiles, slot0 then slot1):
//   P1: stage S8t+7 ; read ALL 24 frags of slot0 ; bar ; lgkm0 ; 16 MFMA ; bar
//   P2: stage S8t+8 ; bar ; 16 MFMA ; bar          (quadrants of acc[8][4])
//   P3: stage S8t+9 ; bar ; 16 MFMA ; bar
//   P4: stage S8t+10; vmcnt(6|0 last) ; bar ; 16 MFMA ; bar
//   P5-P8: same with slot1, vmcnt(6) at P8.
// Half-tile stream S_j (j>>2 = K-tile, j&3 = {A-h0,A-h1,B-h0,B-h1}): one
// half staged per phase, 3 half-tiles (6 loads/wave) in flight at each
// vmcnt(6) -> "all but last 3 halves landed", which is exactly what the
// LDFRAGS at P1/P5 need. A slot is fully read into registers within one
// phase (lgkmcnt(0) before that phase's MFMAs), so stages into it, issued
// only in later phases, cannot WAR-race.

#define G8_BARRIER() do { asm volatile("" ::: "memory"); \
    __builtin_amdgcn_s_barrier(); \
    asm volatile("" ::: "memory"); } while (0)
#define G8_LGKM0() do { asm volatile("s_waitcnt lgkmcnt(0)" ::: "memory"); \
    __builtin_amdgcn_sched_barrier(0); } while (0)
#define G8_VMCNT(n) asm volatile("s_waitcnt vmcnt(" #n ")" ::: "memory")

template <int C>
__device__ __forceinline__ void g8_stage(
    int t, int nt4, const bf16_t* pA, size_t hK64,
    const bf16_t* pB0, const bf16_t* pB1, const bf16_t* pB2, const bf16_t* pB3,
    unsigned dbase, bf16_t* lds)
{
    constexpr int w = C & 3;                          // 0=A-h0 1=A-h1 2=B-h0 3=B-h1
    constexpr unsigned so = (((C >> 2) & 1) ? 65536u : 0u) + (unsigned)w * 16384u;
    int j = 8 * t + C;
    if (j >= nt4) return;                             // uniform tail guard
    size_t goff = (size_t)(j >> 2) * 64;              // K-tile column offset
    const bf16_t *g0, *g1;
    if constexpr (w == 0)      { g0 = pA;              g1 = pA + hK64; }
    else if constexpr (w == 1) { g0 = pA + 2 * hK64;   g1 = pA + 3 * hK64; }
    else if constexpr (w == 2) { g0 = pB0;             g1 = pB1; }
    else                       { g0 = pB2;             g1 = pB3; }
    gld_lds16(g0 + goff, (char*)lds + (so + dbase));
    gld_lds16(g1 + goff, (char*)lds + (so + 8192u + dbase));
}

template <bool RES, typename OT>
__global__ __launch_bounds__(512, 2) void gemm8p(
    const bf16_t* __restrict__ X, const bf16_t* __restrict__ W,
    const float* __restrict__ R, OT* __restrict__ O,
    int N, int K, int ldo)
{
    __shared__ __attribute__((aligned(1024))) bf16_t lds[65536];   // 128 KiB

    const int tid  = threadIdx.x;
    const int lane = tid & 63;
    const int wid  = tid >> 6;
    const int wr   = wid >> 2;          // wave row 0..1  (128 M-rows each)
    const int wc   = wid & 3;           // wave col 0..3  (64 N-cols each)

    // T1: bijective XCD-aware swizzle (m204)
    int nx   = gridDim.x;
    int nwg  = nx * gridDim.y;
    int orig = blockIdx.x + nx * blockIdx.y;
    int qx = nwg >> 3, rx = nwg & 7;
    int xcd = orig & 7, l8 = orig >> 3;
    int wg = (xcd < rx ? xcd * (qx + 1) : rx * (qx + 1) + (xcd - rx) * qx) + l8;
    int m0 = (wg / nx) * 256;
    int n0 = (wg % nx) * 256;

    const int NT    = K >> 6;           // K-tiles (BK=64); NT even (K%128==0)
    const int nt4   = NT << 2;          // half-tile stream length
    const int niter = NT >> 1;

    // ---- stage addressing: thread tid's 16 B lands at linear LDS byte
    // p = i*8192 + tid*16 of a half-tile region; the element that belongs
    // there under the read-side swizzle is (lrow [+64 for i=1], lcol):
    int lrow = ((tid >> 7) << 4) + ((tid >> 2) & 15);
    int cb   = (tid & 3) * 16;
    int cblg = cb ^ (((tid >> 2) & 8) ? 32 : 0);      // inverse == forward (XOR)
    int lcol = (((tid >> 6) & 1) << 5) + (cblg >> 1);
    const size_t hK64 = (size_t)K << 6;               // 64 rows worth of K
    const bf16_t* pA = X + (size_t)(m0 + lrow) * K + lcol;
    const bf16_t* pB[4];
#pragma unroll
    for (int hi = 0; hi < 4; ++hi) {                  // hi = h*2 + i
        int rw = n0 + (hi >> 1) * 128 + (hi & 1) * 64 + lrow;
        if (rw > N - 1) rw = N - 1;                   // clamp OOB W rows
        pB[hi] = W + (size_t)rw * K + lcol;
    }
    const unsigned dbase = (unsigned)tid * 16u;

    // ---- LDS read bases (swizzled): frag (mi|ni, ks) at +(idx*2+ks)*1024
    unsigned c2s = ((unsigned)(lane >> 4) << 4) ^ ((lane & 8) ? 32u : 0u);
    unsigned rdA = (unsigned)(wr * 16384 + (lane & 15) * 64) + c2s;
    unsigned rdB = 32768u + (unsigned)((wc >> 1) * 16384 + (wc & 1) * 8192
                                       + (lane & 15) * 64) + c2s;

    f32x4 acc[8][4] = {};
    bf16x8 a[8][2], b[4][2];

#define G8_STG(C) g8_stage<C>(t, nt4, pA, hK64, pB[0], pB[1], pB[2], pB[3], dbase, lds)
#define G8_LDFRAGS(SO) do { \
    const char* pa_ = (const char*)lds + (SO) + rdA; \
    const char* pb_ = (const char*)lds + (SO) + rdB; \
    _Pragma("unroll") for (int mi = 0; mi < 8; ++mi) { \
        a[mi][0] = *(const bf16x8*)(pa_ + mi * 2048); \
        a[mi][1] = *(const bf16x8*)(pa_ + mi * 2048 + 1024); } \
    _Pragma("unroll") for (int ni = 0; ni < 4; ++ni) { \
        b[ni][0] = *(const bf16x8*)(pb_ + ni * 2048); \
        b[ni][1] = *(const bf16x8*)(pb_ + ni * 2048 + 1024); } \
} while (0)
#define G8_MFMAQ(MI0, NI0) do { \
    __builtin_amdgcn_s_setprio(1); \
    _Pragma("unroll") for (int mi = 0; mi < 4; ++mi) \
    _Pragma("unroll") for (int ni = 0; ni < 2; ++ni) \
    _Pragma("unroll") for (int ks = 0; ks < 2; ++ks) \
        acc[(MI0) + mi][(NI0) + ni] = __builtin_amdgcn_mfma_f32_16x16x32_bf16( \
            a[(MI0) + mi][ks], b[(NI0) + ni][ks], acc[(MI0) + mi][(NI0) + ni], 0, 0, 0); \
    __builtin_amdgcn_s_setprio(0); \
} while (0)

    // ---- prologue: stage S_0..S_6 (tile0 full + tile1 A-h0/A-h1/B-h0)
    {
        int t = 0;
        G8_STG(0); G8_STG(1); G8_STG(2); G8_STG(3);
        G8_STG(4); G8_STG(5); G8_STG(6);
    }
    G8_VMCNT(6);            // tile0 (first 8 loads) landed
    G8_BARRIER();

#pragma unroll 1
    for (int t = 0; t < niter; ++t) {
        // ---- P1 (slot0 = tile 2t)
        G8_STG(7);                       // B-h1 of tile 2t+1 -> slot1
        G8_LDFRAGS(0u);
        G8_BARRIER(); G8_LGKM0();
        G8_MFMAQ(0, 0);
        G8_BARRIER();
        // ---- P2
        G8_STG(8);                       // A-h0 of tile 2t+2 -> slot0
        G8_BARRIER();
        G8_MFMAQ(0, 2);
        G8_BARRIER();
        // ---- P3
        G8_STG(9);
        G8_BARRIER();
        G8_MFMAQ(4, 0);
        G8_BARRIER();
        // ---- P4
        G8_STG(10);
        if (t == niter - 1) { G8_VMCNT(0); } else { G8_VMCNT(6); }
        G8_BARRIER();
        G8_MFMAQ(4, 2);
        G8_BARRIER();
        // ---- P5 (slot1 = tile 2t+1)
        G8_STG(11);                      // B-h1 of tile 2t+2 -> slot0
        G8_LDFRAGS(65536u);
        G8_BARRIER(); G8_LGKM0();
        G8_MFMAQ(0, 0);
        G8_BARRIER();
        // ---- P6
        G8_STG(12);                      // A-h0 of tile 2t+3 -> slot1
        G8_BARRIER();
        G8_MFMAQ(0, 2);
        G8_BARRIER();
        // ---- P7
        G8_STG(13);
        G8_BARRIER();
        G8_MFMAQ(4, 0);
        G8_BARRIER();
        // ---- P8
        G8_STG(14);
        G8_VMCNT(6);
        G8_BARRIER();
        G8_MFMAQ(4, 2);
        G8_BARRIER();
    }

#undef G8_STG
#undef G8_LDFRAGS
#undef G8_MFMAQ

    // ---- epilogue: C/D layout col=lane&15, row=(lane>>4)*4+reg
#pragma unroll
    for (int mi = 0; mi < 8; ++mi)
#pragma unroll
        for (int ni = 0; ni < 4; ++ni) {
            int n = n0 + wc * 64 + ni * 16 + (lane & 15);
            if (n >= N) continue;
            int mbase = m0 + wr * 128 + mi * 16 + (lane >> 4) * 4;
#pragma unroll
            for (int r = 0; r < 4; ++r) {
                size_t off = (size_t)(mbase + r) * ldo + n;
                float v = acc[mi][ni][r];
                if (RES) v += R[off];
                O[off] = (OT)v;
            }
        }
}

// ---------------------------------------------------------------------------
// causal depthwise conv1d (taps=4): rolling registers per channel.
__global__ __launch_bounds__(256) void conv_kernel(
    const bf16_t* __restrict__ zx, const float* __restrict__ cw,
    const float* __restrict__ cb, bf16_t* __restrict__ out)
{
    int c = blockIdx.x * 256 + threadIdx.x;   // 0..6143
    int l0 = blockIdx.y * 128;
    int b = blockIdx.z;
    float w0 = cw[c * 4 + 0], w1 = cw[c * 4 + 1];
    float w2 = cw[c * 4 + 2], w3 = cw[c * 4 + 3];
    float bias = cb[c];
    const bf16_t* src = zx + (size_t)b * L_SEQ * D_IN_PROJ + 2048 + c;
    bf16_t* dst = out + (size_t)b * L_SEQ * CONV_DIM + c;
    float xm3 = (l0 >= 3) ? (float)src[(size_t)(l0 - 3) * D_IN_PROJ] : 0.f;
    float xm2 = (l0 >= 2) ? (float)src[(size_t)(l0 - 2) * D_IN_PROJ] : 0.f;
    float xm1 = (l0 >= 1) ? (float)src[(size_t)(l0 - 1) * D_IN_PROJ] : 0.f;
    for (int l = l0; l < l0 + 128; ++l) {
        float xc = (float)src[(size_t)l * D_IN_PROJ];
        float r = bias + xm3 * w0 + xm2 * w1 + xm1 * w2 + xc * w3;
        dst[(size_t)l * CONV_DIM] = (bf16_t)r;
        xm3 = xm2; xm2 = xm1; xm1 = xc;
    }
}

// ---------------------------------------------------------------------------
// SSM scan pass A: per-(b,h,chunk) state-only scan over Q=128 steps.
__global__ __launch_bounds__(256) void scan_state_kernel(
    const bf16_t* __restrict__ conv, const bf16_t* __restrict__ zx,
    float* __restrict__ Schunk, float* __restrict__ Aprod)
{
    const int SS = 32;
    __shared__ __attribute__((aligned(16))) float xs[SS][64];
    __shared__ __attribute__((aligned(16))) float bs[SS][64];
    __shared__ float as_[SS];

    int k = blockIdx.x, h = blockIdx.y, b = blockIdx.z;
    int tid = threadIdx.x, lane = tid & 63, wv = tid >> 6;
    int pt = tid >> 3, nt = tid & 7;
    int p0 = pt * 2, n0 = nt * 8;

    float st0[8] = {0, 0, 0, 0, 0, 0, 0, 0};
    float st1[8] = {0, 0, 0, 0, 0, 0, 0, 0};
    float aprod = 1.f;

    const bf16_t* cbase = conv + (size_t)b * L_SEQ * CONV_DIM + h * 64;
    const bf16_t* abase = zx + (size_t)b * L_SEQ * D_IN_PROJ + 8192 + h;

    int tstart = k * QCHUNK;
    for (int t0 = tstart; t0 < tstart + QCHUNK; t0 += SS) {
        int soff = (wv >> 1) * 16;
        for (int s = 0; s < 16; ++s) {
            size_t row = (size_t)(t0 + soff + s);
            if ((wv & 1) == 0) xs[soff + s][lane] = (float)cbase[row * CONV_DIM + lane];
            else               bs[soff + s][lane] = (float)cbase[row * CONV_DIM + 2048 + lane];
        }
        if (tid < SS) {
            float v = (float)abase[(size_t)(t0 + tid) * D_IN_PROJ];
            as_[tid] = 1.f / (1.f + __expf(v));     // exp(-softplus(v))
        }
        __syncthreads();
        for (int s = 0; s < SS; ++s) {
            float a = as_[s];
            float x0 = xs[s][p0], x1 = xs[s][p0 + 1];
            aprod *= a;
#pragma unroll
            for (int j = 0; j < 8; ++j) {
                float Bv = bs[s][n0 + j];
                st0[j] = a * st0[j] + x0 * Bv;
                st1[j] = a * st1[j] + x1 * Bv;
            }
        }
        __syncthreads();
    }
    size_t base = (((size_t)(b * N_HEADS + h)) * KCHUNKS + k) * 4096;
    float4* d0 = (float4*)&Schunk[base + p0 * 64 + n0];
    d0[0] = make_float4(st0[0], st0[1], st0[2], st0[3]);
    d0[1] = make_float4(st0[4], st0[5], st0[6], st0[7]);
    float4* d1 = (float4*)&Schunk[base + (p0 + 1) * 64 + n0];
    d1[0] = make_float4(st1[0], st1[1], st1[2], st1[3]);
    d1[1] = make_float4(st1[4], st1[5], st1[6], st1[7]);
    if (tid == 0) Aprod[(b * N_HEADS + h) * KCHUNKS + k] = aprod;
}

// ---------------------------------------------------------------------------
// SSM scan pass B: elementwise inter-chunk combine.
__global__ __launch_bounds__(256) void scan_combine_kernel(
    const float* __restrict__ Schunk, const float* __restrict__ Aprod,
    float* __restrict__ Sinit)
{
    int bh = blockIdx.x >> 4;
    int e = (blockIdx.x & 15) * 256 + threadIdx.x;   // 0..4095
    size_t base = (size_t)bh * KCHUNKS * 4096 + e;
    float S = 0.f;
    for (int k = 0; k < KCHUNKS; ++k) {
        Sinit[base + (size_t)k * 4096] = S;
        float ap = Aprod[bh * KCHUNKS + k];
        S = ap * S + Schunk[base + (size_t)k * 4096];
    }
}

// ---------------------------------------------------------------------------
// SSM scan pass C: per-(b,h,chunk) output scan from Sinit. Fuses y += D*x and
// gated = y*silu(z+zb); writes bf16 [NTOK, 2048]. grid (K,H,B).
__global__ __launch_bounds__(256) void scan_out_kernel(
    const bf16_t* __restrict__ conv, const bf16_t* __restrict__ zx,
    const float* __restrict__ Sinit, const float* __restrict__ Dp,
    const float* __restrict__ zb, bf16_t* __restrict__ gated)
{
    const int S = 16;
    __shared__ __attribute__((aligned(16))) float xs[S][64];
    __shared__ __attribute__((aligned(16))) float bs[S][64];
    __shared__ __attribute__((aligned(16))) float cs[S][64];
    __shared__ __attribute__((aligned(16))) float zs[S][64];
    __shared__ float as_[S];

    int k = blockIdx.x, h = blockIdx.y, b = blockIdx.z;
    int tid = threadIdx.x;
    int lane = tid & 63, wv = tid >> 6;
    int pt = tid >> 3, nt = tid & 7;
    int p0 = pt * 2, n0 = nt * 8;

    size_t sbase = (((size_t)(b * N_HEADS + h)) * KCHUNKS + k) * 4096;
    float4 v00 = *(const float4*)&Sinit[sbase + p0 * 64 + n0];
    float4 v01 = *(const float4*)&Sinit[sbase + p0 * 64 + n0 + 4];
    float4 v10 = *(const float4*)&Sinit[sbase + (p0 + 1) * 64 + n0];
    float4 v11 = *(const float4*)&Sinit[sbase + (p0 + 1) * 64 + n0 + 4];
    float st0[8] = {v00.x, v00.y, v00.z, v00.w, v01.x, v01.y, v01.z, v01.w};
    float st1[8] = {v10.x, v10.y, v10.z, v10.w, v11.x, v11.y, v11.z, v11.w};

    float Dh  = Dp[h];
    float zb0 = zb[h * 64 + p0];
    float zb1 = zb[h * 64 + p0 + 1];

    const bf16_t* cbase = conv + (size_t)b * L_SEQ * CONV_DIM + h * 64;
    const bf16_t* zbase = zx + (size_t)b * L_SEQ * D_IN_PROJ + h * 64;
    const bf16_t* abase = zx + (size_t)b * L_SEQ * D_IN_PROJ + 8192 + h;
    bf16_t* obase = gated + (size_t)b * L_SEQ * D_INNER + h * 64;

    int tstart = k * QCHUNK;
    for (int t0 = tstart; t0 < tstart + QCHUNK; t0 += S) {
        for (int s = 0; s < S; ++s) {
            size_t row = (size_t)(t0 + s);
            if (wv == 0)      xs[s][lane] = (float)cbase[row * CONV_DIM + lane];
            else if (wv == 1) bs[s][lane] = (float)cbase[row * CONV_DIM + 2048 + lane];
            else if (wv == 2) cs[s][lane] = (float)cbase[row * CONV_DIM + 4096 + lane];
            else              zs[s][lane] = (float)zbase[row * D_IN_PROJ + lane];
        }
        if (tid < S) {
            float v = (float)abase[(size_t)(t0 + tid) * D_IN_PROJ];
            as_[tid] = 1.f / (1.f + __expf(v));     // exp(-softplus(v))
        }
        __syncthreads();

        for (int s = 0; s < S; ++s) {
            float a = as_[s];
            float x0 = xs[s][p0], x1 = xs[s][p0 + 1];
            float part0 = 0.f, part1 = 0.f;
#pragma unroll
            for (int j = 0; j < 8; ++j) {
                float Bv = bs[s][n0 + j];
                float Cv = cs[s][n0 + j];
                st0[j] = a * st0[j] + x0 * Bv;
                st1[j] = a * st1[j] + x1 * Bv;
                part0 += st0[j] * Cv;
                part1 += st1[j] * Cv;
            }
            for (int o = 1; o < 8; o <<= 1) {
                part0 += __shfl_xor(part0, o, 64);
                part1 += __shfl_xor(part1, o, 64);
            }
            if (nt == 0) {
                float y0 = part0 + Dh * x0;
                float y1 = part1 + Dh * x1;
                float z0 = zs[s][p0] + zb0;
                float z1 = zs[s][p0 + 1] + zb1;
                y0 *= z0 / (1.f + __expf(-z0));
                y1 *= z1 / (1.f + __expf(-z1));
                bf16_t* o2 = obase + (size_t)(t0 + s) * D_INNER + p0;
                o2[0] = (bf16_t)y0;
                o2[1] = (bf16_t)y1;
            }
        }
        __syncthreads();
    }
}

// ---------------------------------------------------------------------------
// act = bf16(silu(g) * u) from the fused gate|up GEMM output gu [NTOK, 11008]
// (g = cols [0,5504), u = cols [5504,11008)); writes compact [NTOK, 5504].
__global__ __launch_bounds__(256) void act_kernel(
    const bf16_t* __restrict__ gu, bf16_t* __restrict__ act, int n8)
{
    int i = blockIdx.x * 256 + threadIdx.x;
    if (i >= n8) return;
    int row = i / (INTER / 8);
    int c8  = i % (INTER / 8);
    const bf16x8* g = (const bf16x8*)(gu + (size_t)row * (2 * INTER)) + c8;
    const bf16x8* u = (const bf16x8*)(gu + (size_t)row * (2 * INTER) + INTER) + c8;
    bf16x8 gv = *g, uv = *u, r;
#pragma unroll
    for (int j = 0; j < 8; ++j) {
        float x = (float)gv[j];
        r[j] = (bf16_t)((x / (1.f + __expf(-x))) * (float)uv[j]);
    }
    ((bf16x8*)act)[i] = r;
}

// ---------------------------------------------------------------------------
extern "C" void kernel_launch(void* const* d_in, const int* in_sizes, int n_in,
                              void* d_out, int out_size, void* d_ws, size_t ws_size,
                              hipStream_t stream) {
    const float* hidden     = (const float*)d_in[0];
    const float* mask       = (const float*)d_in[1];
    const float* in_proj_w  = (const float*)d_in[2];
    const float* conv_w     = (const float*)d_in[3];
    const float* conv_b     = (const float*)d_in[4];
    const float* z_bias     = (const float*)d_in[5];
    const float* Dvec       = (const float*)d_in[6];
    const float* out_proj_w = (const float*)d_in[7];
    const float* ln1_w      = (const float*)d_in[8];
    const float* ln2_w      = (const float*)d_in[9];
    const float* gate_w     = (const float*)d_in[10];
    const float* up_w       = (const float*)d_in[11];
    const float* down_w     = (const float*)d_in[12];
    float* out = (float*)d_out;          // [4096, 2048] f32; holds h2 from step 5 on

    // workspace arena (184,942,592 B total):
    // steps 1-5 (old layout):
    //   [0, 67371008)          zxb bf16 [4096,8224]
    //   [67371008, 117702656)  convo bf16 [4096,6144]
    //   [117702656, 134479872) hn (1-2) / gated (4-5) bf16 [4096,2048]
    //   [134479872, 151257088) Schunk f32 16MB (scan)
    //   [151257088, 184942592) wbuf bf16 33.7MB (in_proj/out_proj weights)
    //                          / Sinit f32 16MB + Aprod 4KB (scan)
    // steps 6-9 (everything above dead):
    //   [0, 90177536)          guO bf16 [4096,11008] (gate|up GEMM out)
    //   [90177536, 135266304)  guW bf16 [11008,2048] weights, then actO
    //   [135266304, 152043520) h2n bf16 [4096,2048], then dwW bf16 [2048,5504]
    char* ws = (char*)d_ws;
    bf16_t* zxb    = (bf16_t*)(ws + 0);
    bf16_t* convo  = (bf16_t*)(ws + 67371008);
    bf16_t* hn     = (bf16_t*)(ws + 117702656);
    bf16_t* gated  = (bf16_t*)(ws + 117702656);
    float*  Schunk = (float*) (ws + 134479872);
    bf16_t* wbuf   = (bf16_t*)(ws + 151257088);
    float*  Sinit  = (float*) (ws + 151257088);   // scan-only, aliases wbuf
    float*  Aprod  = (float*) (ws + 168034304);
    bf16_t* guO    = (bf16_t*)(ws + 0);           // steps 7-8
    bf16_t* guW    = (bf16_t*)(ws + 90177536);    // step 7
    bf16_t* actO   = (bf16_t*)(ws + 90177536);    // step 8-9 (reuses guW)
    bf16_t* h2n    = (bf16_t*)(ws + 135266304);   // steps 6-7
    bf16_t* dwW    = (bf16_t*)(ws + 135266304);   // step 9 (reuses h2n)

    // 1. hn = rmsnorm(hidden, ln1) * mask        (bf16)
    rmsnorm_kernel<<<NTOK, 256, 0, stream>>>(hidden, ln1_w, mask, hn);
    // 2. zxb = hn @ in_proj^T  [4096, 8224]: main 8192 cols via 256^2 8-phase
    //    (grid 512 = exactly 2 full GPU rounds), A_log strip (32 cols) via
    //    the 128-tile kernel.
    cvt_kernel<<<8224, 256, 0, stream>>>(in_proj_w, wbuf, D_IN_PROJ * D_MODEL / 8);
    gemm8p<false, bf16_t><<<dim3(32, 16), 512, 0, stream>>>(
        hn, wbuf, nullptr, zxb, 8192, D_MODEL, D_IN_PROJ);
    gemm_bt<false, bf16_t><<<dim3(1, 32), 256, 0, stream>>>(
        hn, wbuf + (size_t)8192 * D_MODEL, nullptr, zxb + 8192, 32, D_MODEL, D_IN_PROJ);
    // 3. causal depthwise conv on xBC cols
    conv_kernel<<<dim3(24, 16, 2), 256, 0, stream>>>(zxb, conv_w, conv_b, convo);
    // 4. chunk-parallel SSM scan (A: chunk states, B: combine, C: outputs)
    scan_state_kernel<<<dim3(KCHUNKS, N_HEADS, BATCH), 256, 0, stream>>>(convo, zxb, Schunk, Aprod);
    scan_combine_kernel<<<1024, 256, 0, stream>>>(Schunk, Aprod, Sinit);
    scan_out_kernel<<<dim3(KCHUNKS, N_HEADS, BATCH), 256, 0, stream>>>(convo, zxb, Sinit, Dvec, z_bias, gated);
    // 5. h2 = gated @ out_proj^T + hidden        (f32, stored in d_out)
    cvt_kernel<<<2048, 256, 0, stream>>>(out_proj_w, wbuf, D_MODEL * D_INNER / 8);
    gemm_bt<true, float><<<dim3(16, 32), 256, 0, stream>>>(
        gated, wbuf, hidden, out, D_MODEL, D_INNER, D_MODEL);
    // 6. h2n = rmsnorm(h2, ln2)                  (bf16)
    rmsnorm_kernel<<<NTOK, 256, 0, stream>>>(out, ln2_w, nullptr, h2n);
    // 7. fused gate|up: guO = h2n @ [gate_w; up_w]^T  [4096, 11008]
    //    (11008 = 43*256 exactly -> one 688-block 8-phase GEMM instead of
    //     two 352-block ones: kills a dispatch + wave-quantization waste)
    cvt_kernel<<<5504, 256, 0, stream>>>(gate_w, guW, INTER * D_MODEL / 8);
    cvt_kernel<<<5504, 256, 0, stream>>>(up_w, guW + (size_t)INTER * D_MODEL, INTER * D_MODEL / 8);
    gemm8p<false, bf16_t><<<dim3(43, 16), 512, 0, stream>>>(
        h2n, guW, nullptr, guO, 2 * INTER, D_MODEL, 2 * INTER);
    // 8. actO = silu(g)*u                        (compact [4096, 5504])
    act_kernel<<<11008, 256, 0, stream>>>(guO, actO, NTOK * INTER / 8);
    // 9. out = actO @ down_w^T + h2              (f32, in-place residual)
    cvt_kernel<<<5504, 256, 0, stream>>>(down_w, dwW, D_MODEL * INTER / 8);
    gemm_bt<true, float><<<dim3(16, 32), 256, 0, stream>>>(
        actO, dwW, out, out, D_MODEL, INTER, D_MODEL);
}

// Round 2
// 1041.197 us; speedup vs baseline: 1.1294x; 1.1294x over previous
//
#include <hip/hip_runtime.h>
#include <math.h>

typedef __bf16 bf16_t;
typedef __attribute__((ext_vector_type(8))) __bf16 bf16x8;
typedef __attribute__((ext_vector_type(4))) float f32x4;

#define D_MODEL   2048
#define L_SEQ     2048
#define BATCH     2
#define NTOK      4096      // BATCH * L_SEQ
#define N_HEADS   32
#define D_STATE   64
#define HEADDIM   64
#define D_INNER   2048
#define CONV_DIM  6144      // d_inner + 2*H*N
#define D_IN_PROJ 8224      // 2*d_inner + 2*H*N + H
#define INTER     5504
#define QCHUNK    128       // scan chunk length
#define KCHUNKS   16        // L_SEQ / QCHUNK

// ---------------------------------------------------------------------------
// async global->LDS (width 16B). HW dest = wave-uniform base + lane*16; our
// LDS layouts are linear in tid*16 so per-lane pointers match HW placement.
__device__ __forceinline__ void gld_lds16(const void* g, void* l) {
    __builtin_amdgcn_global_load_lds(
        (const __attribute__((address_space(1))) unsigned int*)g,
        (__attribute__((address_space(3))) unsigned int*)l, 16, 0, 0);
}

// ---------------------------------------------------------------------------
// f32 -> bf16 convert, 8 elems/thread
__global__ __launch_bounds__(256) void cvt_kernel(
    const float* __restrict__ s, bf16_t* __restrict__ d, int n8)
{
    int i = blockIdx.x * 256 + threadIdx.x;
    if (i >= n8) return;
    const float4* s4 = (const float4*)s;
    float4 a = s4[2 * i], b = s4[2 * i + 1];
    bf16x8 r;
    r[0] = (bf16_t)a.x; r[1] = (bf16_t)a.y; r[2] = (bf16_t)a.z; r[3] = (bf16_t)a.w;
    r[4] = (bf16_t)b.x; r[5] = (bf16_t)b.y; r[6] = (bf16_t)b.z; r[7] = (bf16_t)b.w;
    ((bf16x8*)d)[i] = r;
}

// ---------------------------------------------------------------------------
// RMSNorm: one block per token row; f32 in, bf16 out.
__global__ __launch_bounds__(256) void rmsnorm_kernel(
    const float* __restrict__ x, const float* __restrict__ w,
    const float* __restrict__ mask, bf16_t* __restrict__ out)
{
    __shared__ float red[4];
    __shared__ float sinv;
    int row = blockIdx.x;
    const float* xr = x + (size_t)row * D_MODEL;
    float xv[8];
    float ss = 0.f;
#pragma unroll
    for (int i = 0; i < 8; ++i) {
        float v = xr[threadIdx.x + 256 * i];
        xv[i] = v;
        ss += v * v;
    }
    for (int off = 32; off >= 1; off >>= 1) ss += __shfl_down(ss, off, 64);
    int lane = threadIdx.x & 63, wv = threadIdx.x >> 6;
    if (lane == 0) red[wv] = ss;
    __syncthreads();
    if (threadIdx.x == 0) {
        float t = red[0] + red[1] + red[2] + red[3];
        sinv = rsqrtf(t / (float)D_MODEL + 1e-6f);
    }
    __syncthreads();
    float s = sinv;
    float m = mask ? mask[row] : 1.f;
    bf16_t* orow = out + (size_t)row * D_MODEL;
#pragma unroll
    for (int i = 0; i < 8; ++i) {
        int c = threadIdx.x + 256 * i;
        orow[c] = (bf16_t)(xv[i] * s * w[c] * m);
    }
}

// ---------------------------------------------------------------------------
// GEMM (m97 structure, 128x128 tile, BK=32): O[M,N] = X[M,K] @ W[N,K]^T
// (+ optional f32 residual R). Kept for small-N GEMMs (out_proj, down,
// in_proj A_log strip) where the 256^2 kernel would underfill the GPU.
template <bool RES, typename OT>
__global__ __launch_bounds__(256) void gemm_bt(
    const bf16_t* __restrict__ X, const bf16_t* __restrict__ W,
    const float* __restrict__ R, OT* __restrict__ O,
    int N, int K, int ldo)
{
    __shared__ __attribute__((aligned(16))) bf16_t As[128 * 32];
    __shared__ __attribute__((aligned(16))) bf16_t Bs[128 * 32];

    int tid = threadIdx.x;
    int m0 = blockIdx.y * 128;
    int n0 = blockIdx.x * 128;

    f32x4 acc[4][4] = {};

    int lane = tid & 63;
    int wv = tid >> 6;
    int wm = (wv >> 1) * 64, wn = (wv & 1) * 64;
    int lm = lane & 15, lq = lane >> 4;

    int srow = tid >> 2;            // 0..63
    int scol = (tid & 3) * 8;       // element col 0/8/16/24
    const bf16_t* Xp0 = X + (size_t)(m0 + srow) * K + scol;
    const bf16_t* Xp1 = X + (size_t)(m0 + 64 + srow) * K + scol;
    int wr0 = n0 + srow;      if (wr0 > N - 1) wr0 = N - 1;  // clamp OOB rows
    int wr1 = n0 + 64 + srow; if (wr1 > N - 1) wr1 = N - 1;
    const bf16_t* Wp0 = W + (size_t)wr0 * K + scol;
    const bf16_t* Wp1 = W + (size_t)wr1 * K + scol;
    bf16_t* lA0 = &As[tid * 8];
    bf16_t* lA1 = &As[2048 + tid * 8];
    bf16_t* lB0 = &Bs[tid * 8];
    bf16_t* lB1 = &Bs[2048 + tid * 8];

    for (int k0 = 0; k0 < K; k0 += 32) {
        __syncthreads();                 // prev iter's LDS reads done
        gld_lds16(Xp0 + k0, lA0);
        gld_lds16(Xp1 + k0, lA1);
        gld_lds16(Wp0 + k0, lB0);
        gld_lds16(Wp1 + k0, lB1);
        __syncthreads();                 // compiler drains vmcnt before barrier

        bf16x8 a[4], b[4];
#pragma unroll
        for (int i = 0; i < 4; ++i)
            a[i] = *(const bf16x8*)&As[(wm + i * 16 + lm) * 32 + lq * 8];
#pragma unroll
        for (int i = 0; i < 4; ++i)
            b[i] = *(const bf16x8*)&Bs[(wn + i * 16 + lm) * 32 + lq * 8];
#pragma unroll
        for (int mi = 0; mi < 4; ++mi)
#pragma unroll
            for (int ni = 0; ni < 4; ++ni)
                acc[mi][ni] = __builtin_amdgcn_mfma_f32_16x16x32_bf16(
                    a[mi], b[ni], acc[mi][ni], 0, 0, 0);
    }

    // epilogue: C/D layout col=lane&15, row=(lane>>4)*4+reg  [verified m89/m91]
#pragma unroll
    for (int mi = 0; mi < 4; ++mi)
#pragma unroll
        for (int ni = 0; ni < 4; ++ni) {
            int n = n0 + wn + ni * 16 + lm;
            if (n >= N) continue;
            int mbase = m0 + wm + mi * 16 + lq * 4;
#pragma unroll
            for (int r = 0; r < 4; ++r) {
                size_t off = (size_t)(mbase + r) * ldo + n;
                float v = acc[mi][ni][r];
                if (RES) v += R[off];
                O[off] = (OT)v;
            }
        }
}

// ---------------------------------------------------------------------------
// 256x256 8-phase GEMM (T1 XCD swizzle + T2 st_16x32 LDS swizzle + T3/T4
// counted-vmcnt 8-phase + T5 setprio):  O[M,N] = X[M,K] @ W[N,K]^T.
// Requirements: M == gridDim.y*256, K % 128 == 0, N <= gridDim.x*256
// (OOB W rows clamped, OOB cols not stored). 512 threads = 8 waves (2Mx4N),
// per-wave 128x64 output (acc[8][4]); LDS 128 KiB = 2 dbuf slots of
// {A: 2x(128x64), B: 2x(128x64)} bf16.
//
// v2 (spill fix): fragment reads are spread per-phase (12/4/8/0 per K-tile),
// so live frags = a[4][2]+b[4][2] = 64 VGPR (v1 kept 24 frags = 96 VGPR live
// -> spilled: WRITE_SIZE showed +84MB scratch traffic, MfmaUtil 25%).
//
// LDS layout per 16 KiB half-tile: 16-row x 32-col subtiles stored
// contiguously (1024 B), XOR-swizzled; global_load_lds writes linearly
// (tid*16); swizzle applied by pre-permuting the per-lane GLOBAL source
// address (both-sides rule, m104/m201). Region map per 64 KiB slot:
//   A-h0 [0,16K) rows 0..127 | A-h1 [16K,32K) rows 128..255
//   B-h0 [32K,48K) W-rows 0..127 | B-h1 [48K,64K) W-rows 128..255
//
// Read schedule per K-tile (slot SO), one quadrant of acc per phase:
//   Pa: read a-lo (rows +0..63, 8x b128) + b01 (4x) ; MFMA acc[0..3][0..1]
//   Pb: read b23 (4x)                               ; MFMA acc[0..3][2..3]
//   Pc: read a-hi (rows +64..127, 8x, overwrite a)  ; MFMA acc[4..7][0..1]
//   Pd: no reads                                    ; MFMA acc[4..7][2..3]
// Region read-complete: B by end-Pb, A by end-Pc  =>  stage windows for the
// tile that re-uses this slot: B-halves >= Pc's phase+0 (after Pb close),
// A-halves >= Pd. Stage stream (1 half-tile = 2 loads/wave per phase):
//   P1:(2t+1).Ah0 P2:(2t+1).Ah1 P3:(2t+2).Bh0 P4:(2t+2).Bh1
//   P5:(2t+2).Ah0 P6:(2t+2).Ah1 P7:(2t+3).Bh0 P8:(2t+3).Bh1
// Landing guards: vmcnt(4) at P4 (slot1 tile fully landed: outstanding =
// stages P3,P4 only) and at P8 (slot0 tile landed: outstanding = P7,P8).
// Last iteration: vmcnt(0) at P4 (its P2-staged halves have no later
// stages to count against). Prologue: tile0 all 4 halves + tile1 B-halves
// (6 stages), vmcnt(4) = tile0 landed.

#define G8_BARRIER() do { asm volatile("" ::: "memory"); \
    __builtin_amdgcn_s_barrier(); \
    asm volatile("" ::: "memory"); } while (0)
#define G8_LGKM0() do { asm volatile("s_waitcnt lgkmcnt(0)" ::: "memory"); \
    __builtin_amdgcn_sched_barrier(0); } while (0)
#define G8_VMCNT(n) asm volatile("s_waitcnt vmcnt(" #n ")" ::: "memory")

template <int W>
__device__ __forceinline__ void g8_stage(
    int tile, int NT, const bf16_t* pA, size_t hK64,
    const bf16_t* pB0, const bf16_t* pB1, const bf16_t* pB2, const bf16_t* pB3,
    unsigned dbase, bf16_t* lds)
{
    if (tile >= NT) return;                           // uniform tail guard
    unsigned so = ((tile & 1) ? 65536u : 0u) + (unsigned)W * 16384u;
    size_t goff = (size_t)tile * 64;                  // K-tile column offset
    const bf16_t *g0, *g1;
    if constexpr (W == 0)      { g0 = pA;              g1 = pA + hK64; }
    else if constexpr (W == 1) { g0 = pA + 2 * hK64;   g1 = pA + 3 * hK64; }
    else if constexpr (W == 2) { g0 = pB0;             g1 = pB1; }
    else                       { g0 = pB2;             g1 = pB3; }
    gld_lds16(g0 + goff, (char*)lds + (so + dbase));
    gld_lds16(g1 + goff, (char*)lds + (so + 8192u + dbase));
}

template <bool RES, typename OT>
__global__ __launch_bounds__(512, 2) void gemm8p(
    const bf16_t* __restrict__ X, const bf16_t* __restrict__ W,
    const float* __restrict__ R, OT* __restrict__ O,
    int N, int K, int ldo)
{
    __shared__ __attribute__((aligned(1024))) bf16_t lds[65536];   // 128 KiB

    const int tid  = threadIdx.x;
    const int lane = tid & 63;
    const int wid  = tid >> 6;
    const int wr   = wid >> 2;          // wave row 0..1  (128 M-rows each)
    const int wc   = wid & 3;           // wave col 0..3  (64 N-cols each)

    // T1: bijective XCD-aware swizzle (m204)
    int nx   = gridDim.x;
    int nwg  = nx * gridDim.y;
    int orig = blockIdx.x + nx * blockIdx.y;
    int qx = nwg >> 3, rx = nwg & 7;
    int xcd = orig & 7, l8 = orig >> 3;
    int wg = (xcd < rx ? xcd * (qx + 1) : rx * (qx + 1) + (xcd - rx) * qx) + l8;
    int m0 = (wg / nx) * 256;
    int n0 = (wg % nx) * 256;

    const int NT    = K >> 6;           // K-tiles (BK=64); NT even (K%128==0)
    const int niter = NT >> 1;

    // ---- stage addressing: thread tid's 16 B lands at linear LDS byte
    // p = i*8192 + tid*16 of a half-tile region; the element that belongs
    // there under the read-side swizzle is (lrow [+64 for i=1], lcol):
    int lrow = ((tid >> 7) << 4) + ((tid >> 2) & 15);
    int cb   = (tid & 3) * 16;
    int cblg = cb ^ (((tid >> 2) & 8) ? 32 : 0);      // inverse == forward (XOR)
    int lcol = (((tid >> 6) & 1) << 5) + (cblg >> 1);
    const size_t hK64 = (size_t)K << 6;               // 64 rows worth of K
    const bf16_t* pA = X + (size_t)(m0 + lrow) * K + lcol;
    const bf16_t* pB[4];
#pragma unroll
    for (int hi = 0; hi < 4; ++hi) {                  // hi = h*2 + i
        int rw = n0 + (hi >> 1) * 128 + (hi & 1) * 64 + lrow;
        if (rw > N - 1) rw = N - 1;                   // clamp OOB W rows
        pB[hi] = W + (size_t)rw * K + lcol;
    }
    const unsigned dbase = (unsigned)tid * 16u;

    // ---- LDS read bases (swizzled): frag (idx, ks) at +(idx*2+ks)*1024
    unsigned c2s = ((unsigned)(lane >> 4) << 4) ^ ((lane & 8) ? 32u : 0u);
    unsigned rdA = (unsigned)(wr * 16384 + (lane & 15) * 64) + c2s;
    unsigned rdB = 32768u + (unsigned)((wc >> 1) * 16384 + (wc & 1) * 8192
                                       + (lane & 15) * 64) + c2s;

    f32x4 acc[8][4] = {};
    bf16x8 a[4][2], b[4][2];

#define G8_STG(W_, TILE) g8_stage<W_>((TILE), NT, pA, hK64, \
    pB[0], pB[1], pB[2], pB[3], dbase, lds)
#define G8_LDA(SO, HI) do { \
    const char* pa_ = (const char*)lds + (SO) + rdA + (HI) * 8192; \
    _Pragma("unroll") for (int mi = 0; mi < 4; ++mi) { \
        a[mi][0] = *(const bf16x8*)(pa_ + mi * 2048); \
        a[mi][1] = *(const bf16x8*)(pa_ + mi * 2048 + 1024); } \
} while (0)
#define G8_LDB(SO, NI0) do { \
    const char* pb_ = (const char*)lds + (SO) + rdB + (NI0) * 2048; \
    _Pragma("unroll") for (int nj = 0; nj < 2; ++nj) { \
        b[(NI0) + nj][0] = *(const bf16x8*)(pb_ + nj * 2048); \
        b[(NI0) + nj][1] = *(const bf16x8*)(pb_ + nj * 2048 + 1024); } \
} while (0)
#define G8_MFMAQ(MI0, NI0) do { \
    __builtin_amdgcn_s_setprio(1); \
    _Pragma("unroll") for (int mi = 0; mi < 4; ++mi) \
    _Pragma("unroll") for (int ni = 0; ni < 2; ++ni) \
    _Pragma("unroll") for (int ks = 0; ks < 2; ++ks) \
        acc[(MI0) + mi][(NI0) + ni] = __builtin_amdgcn_mfma_f32_16x16x32_bf16( \
            a[mi][ks], b[(NI0) + ni][ks], acc[(MI0) + mi][(NI0) + ni], 0, 0, 0); \
    __builtin_amdgcn_s_setprio(0); \
} while (0)

    // ---- prologue: tile0 all halves + tile1 B-halves
    G8_STG(2, 0); G8_STG(3, 0); G8_STG(0, 0); G8_STG(1, 0);
    G8_STG(2, 1); G8_STG(3, 1);
    G8_VMCNT(4);            // tile0's 8 loads landed
    G8_BARRIER();

#pragma unroll 1
    for (int t = 0; t < niter; ++t) {
        const int t2 = 2 * t;
        // ---- P1 (slot0 = tile 2t): a-lo + b01
        G8_STG(0, t2 + 1);
        G8_LDA(0u, 0); G8_LDB(0u, 0);
        G8_BARRIER(); G8_LGKM0();
        G8_MFMAQ(0, 0);
        G8_BARRIER();
        // ---- P2: b23
        G8_STG(1, t2 + 1);
        G8_LDB(0u, 2);
        G8_BARRIER(); G8_LGKM0();
        G8_MFMAQ(0, 2);
        G8_BARRIER();
        // ---- P3: a-hi
        G8_STG(2, t2 + 2);
        G8_LDA(0u, 1);
        G8_BARRIER(); G8_LGKM0();
        G8_MFMAQ(4, 0);
        G8_BARRIER();
        // ---- P4
        G8_STG(3, t2 + 2);
        if (t == niter - 1) { G8_VMCNT(0); } else { G8_VMCNT(4); }
        G8_BARRIER();
        G8_MFMAQ(4, 2);
        G8_BARRIER();
        // ---- P5 (slot1 = tile 2t+1): a-lo + b01
        G8_STG(0, t2 + 2);
        G8_LDA(65536u, 0); G8_LDB(65536u, 0);
        G8_BARRIER(); G8_LGKM0();
        G8_MFMAQ(0, 0);
        G8_BARRIER();
        // ---- P6: b23
        G8_STG(1, t2 + 2);
        G8_LDB(65536u, 2);
        G8_BARRIER(); G8_LGKM0();
        G8_MFMAQ(0, 2);
        G8_BARRIER();
        // ---- P7: a-hi
        G8_STG(2, t2 + 3);
        G8_LDA(65536u, 1);
        G8_BARRIER(); G8_LGKM0();
        G8_MFMAQ(4, 0);
        G8_BARRIER();
        // ---- P8
        G8_STG(3, t2 + 3);
        G8_VMCNT(4);
        G8_BARRIER();
        G8_MFMAQ(4, 2);
        G8_BARRIER();
    }

#undef G8_STG
#undef G8_LDA
#undef G8_LDB
#undef G8_MFMAQ

    // ---- epilogue: C/D layout col=lane&15, row=(lane>>4)*4+reg
#pragma unroll
    for (int mi = 0; mi < 8; ++mi)
#pragma unroll
        for (int ni = 0; ni < 4; ++ni) {
            int n = n0 + wc * 64 + ni * 16 + (lane & 15);
            if (n >= N) continue;
            int mbase = m0 + wr * 128 + mi * 16 + (lane >> 4) * 4;
#pragma unroll
            for (int r = 0; r < 4; ++r) {
                size_t off = (size_t)(mbase + r) * ldo + n;
                float v = acc[mi][ni][r];
                if (RES) v += R[off];
                O[off] = (OT)v;
            }
        }
}

// ---------------------------------------------------------------------------
// causal depthwise conv1d (taps=4): rolling registers per channel.
__global__ __launch_bounds__(256) void conv_kernel(
    const bf16_t* __restrict__ zx, const float* __restrict__ cw,
    const float* __restrict__ cb, bf16_t* __restrict__ out)
{
    int c = blockIdx.x * 256 + threadIdx.x;   // 0..6143
    int l0 = blockIdx.y * 128;
    int b = blockIdx.z;
    float w0 = cw[c * 4 + 0], w1 = cw[c * 4 + 1];
    float w2 = cw[c * 4 + 2], w3 = cw[c * 4 + 3];
    float bias = cb[c];
    const bf16_t* src = zx + (size_t)b * L_SEQ * D_IN_PROJ + 2048 + c;
    bf16_t* dst = out + (size_t)b * L_SEQ * CONV_DIM + c;
    float xm3 = (l0 >= 3) ? (float)src[(size_t)(l0 - 3) * D_IN_PROJ] : 0.f;
    float xm2 = (l0 >= 2) ? (float)src[(size_t)(l0 - 2) * D_IN_PROJ] : 0.f;
    float xm1 = (l0 >= 1) ? (float)src[(size_t)(l0 - 1) * D_IN_PROJ] : 0.f;
    for (int l = l0; l < l0 + 128; ++l) {
        float xc = (float)src[(size_t)l * D_IN_PROJ];
        float r = bias + xm3 * w0 + xm2 * w1 + xm1 * w2 + xc * w3;
        dst[(size_t)l * CONV_DIM] = (bf16_t)r;
        xm3 = xm2; xm2 = xm1; xm1 = xc;
    }
}

// ---------------------------------------------------------------------------
// SSM scan pass A: per-(b,h,chunk) state-only scan over Q=128 steps.
__global__ __launch_bounds__(256) void scan_state_kernel(
    const bf16_t* __restrict__ conv, const bf16_t* __restrict__ zx,
    float* __restrict__ Schunk, float* __restrict__ Aprod)
{
    const int SS = 32;
    __shared__ __attribute__((aligned(16))) float xs[SS][64];
    __shared__ __attribute__((aligned(16))) float bs[SS][64];
    __shared__ float as_[SS];

    int k = blockIdx.x, h = blockIdx.y, b = blockIdx.z;
    int tid = threadIdx.x, lane = tid & 63, wv = tid >> 6;
    int pt = tid >> 3, nt = tid & 7;
    int p0 = pt * 2, n0 = nt * 8;

    float st0[8] = {0, 0, 0, 0, 0, 0, 0, 0};
    float st1[8] = {0, 0, 0, 0, 0, 0, 0, 0};
    float aprod = 1.f;

    const bf16_t* cbase = conv + (size_t)b * L_SEQ * CONV_DIM + h * 64;
    const bf16_t* abase = zx + (size_t)b * L_SEQ * D_IN_PROJ + 8192 + h;

    int tstart = k * QCHUNK;
    for (int t0 = tstart; t0 < tstart + QCHUNK; t0 += SS) {
        int soff = (wv >> 1) * 16;
        for (int s = 0; s < 16; ++s) {
            size_t row = (size_t)(t0 + soff + s);
            if ((wv & 1) == 0) xs[soff + s][lane] = (float)cbase[row * CONV_DIM + lane];
            else               bs[soff + s][lane] = (float)cbase[row * CONV_DIM + 2048 + lane];
        }
        if (tid < SS) {
            float v = (float)abase[(size_t)(t0 + tid) * D_IN_PROJ];
            as_[tid] = 1.f / (1.f + __expf(v));     // exp(-softplus(v))
        }
        __syncthreads();
        for (int s = 0; s < SS; ++s) {
            float a = as_[s];
            float x0 = xs[s][p0], x1 = xs[s][p0 + 1];
            aprod *= a;
#pragma unroll
            for (int j = 0; j < 8; ++j) {
                float Bv = bs[s][n0 + j];
                st0[j] = a * st0[j] + x0 * Bv;
                st1[j] = a * st1[j] + x1 * Bv;
            }
        }
        __syncthreads();
    }
    size_t base = (((size_t)(b * N_HEADS + h)) * KCHUNKS + k) * 4096;
    float4* d0 = (float4*)&Schunk[base + p0 * 64 + n0];
    d0[0] = make_float4(st0[0], st0[1], st0[2], st0[3]);
    d0[1] = make_float4(st0[4], st0[5], st0[6], st0[7]);
    float4* d1 = (float4*)&Schunk[base + (p0 + 1) * 64 + n0];
    d1[0] = make_float4(st1[0], st1[1], st1[2], st1[3]);
    d1[1] = make_float4(st1[4], st1[5], st1[6], st1[7]);
    if (tid == 0) Aprod[(b * N_HEADS + h) * KCHUNKS + k] = aprod;
}

// ---------------------------------------------------------------------------
// SSM scan pass B: elementwise inter-chunk combine.
__global__ __launch_bounds__(256) void scan_combine_kernel(
    const float* __restrict__ Schunk, const float* __restrict__ Aprod,
    float* __restrict__ Sinit)
{
    int bh = blockIdx.x >> 4;
    int e = (blockIdx.x & 15) * 256 + threadIdx.x;   // 0..4095
    size_t base = (size_t)bh * KCHUNKS * 4096 + e;
    float S = 0.f;
    for (int k = 0; k < KCHUNKS; ++k) {
        Sinit[base + (size_t)k * 4096] = S;
        float ap = Aprod[bh * KCHUNKS + k];
        S = ap * S + Schunk[base + (size_t)k * 4096];
    }
}

// ---------------------------------------------------------------------------
// SSM scan pass C: per-(b,h,chunk) output scan from Sinit. Fuses y += D*x and
// gated = y*silu(z+zb); writes bf16 [NTOK, 2048]. grid (K,H,B).
__global__ __launch_bounds__(256) void scan_out_kernel(
    const bf16_t* __restrict__ conv, const bf16_t* __restrict__ zx,
    const float* __restrict__ Sinit, const float* __restrict__ Dp,
    const float* __restrict__ zb, bf16_t* __restrict__ gated)
{
    const int S = 16;
    __shared__ __attribute__((aligned(16))) float xs[S][64];
    __shared__ __attribute__((aligned(16))) float bs[S][64];
    __shared__ __attribute__((aligned(16))) float cs[S][64];
    __shared__ __attribute__((aligned(16))) float zs[S][64];
    __shared__ float as_[S];

    int k = blockIdx.x, h = blockIdx.y, b = blockIdx.z;
    int tid = threadIdx.x;
    int lane = tid & 63, wv = tid >> 6;
    int pt = tid >> 3, nt = tid & 7;
    int p0 = pt * 2, n0 = nt * 8;

    size_t sbase = (((size_t)(b * N_HEADS + h)) * KCHUNKS + k) * 4096;
    float4 v00 = *(const float4*)&Sinit[sbase + p0 * 64 + n0];
    float4 v01 = *(const float4*)&Sinit[sbase + p0 * 64 + n0 + 4];
    float4 v10 = *(const float4*)&Sinit[sbase + (p0 + 1) * 64 + n0];
    float4 v11 = *(const float4*)&Sinit[sbase + (p0 + 1) * 64 + n0 + 4];
    float st0[8] = {v00.x, v00.y, v00.z, v00.w, v01.x, v01.y, v01.z, v01.w};
    float st1[8] = {v10.x, v10.y, v10.z, v10.w, v11.x, v11.y, v11.z, v11.w};

    float Dh  = Dp[h];
    float zb0 = zb[h * 64 + p0];
    float zb1 = zb[h * 64 + p0 + 1];

    const bf16_t* cbase = conv + (size_t)b * L_SEQ * CONV_DIM + h * 64;
    const bf16_t* zbase = zx + (size_t)b * L_SEQ * D_IN_PROJ + h * 64;
    const bf16_t* abase = zx + (size_t)b * L_SEQ * D_IN_PROJ + 8192 + h;
    bf16_t* obase = gated + (size_t)b * L_SEQ * D_INNER + h * 64;

    int tstart = k * QCHUNK;
    for (int t0 = tstart; t0 < tstart + QCHUNK; t0 += S) {
        for (int s = 0; s < S; ++s) {
            size_t row = (size_t)(t0 + s);
            if (wv == 0)      xs[s][lane] = (float)cbase[row * CONV_DIM + lane];
            else if (wv == 1) bs[s][lane] = (float)cbase[row * CONV_DIM + 2048 + lane];
            else if (wv == 2) cs[s][lane] = (float)cbase[row * CONV_DIM + 4096 + lane];
            else              zs[s][lane] = (float)zbase[row * D_IN_PROJ + lane];
        }
        if (tid < S) {
            float v = (float)abase[(size_t)(t0 + tid) * D_IN_PROJ];
            as_[tid] = 1.f / (1.f + __expf(v));     // exp(-softplus(v))
        }
        __syncthreads();

        for (int s = 0; s < S; ++s) {
            float a = as_[s];
            float x0 = xs[s][p0], x1 = xs[s][p0 + 1];
            float part0 = 0.f, part1 = 0.f;
#pragma unroll
            for (int j = 0; j < 8; ++j) {
                float Bv = bs[s][n0 + j];
                float Cv = cs[s][n0 + j];
                st0[j] = a * st0[j] + x0 * Bv;
                st1[j] = a * st1[j] + x1 * Bv;
                part0 += st0[j] * Cv;
                part1 += st1[j] * Cv;
            }
            for (int o = 1; o < 8; o <<= 1) {
                part0 += __shfl_xor(part0, o, 64);
                part1 += __shfl_xor(part1, o, 64);
            }
            if (nt == 0) {
                float y0 = part0 + Dh * x0;
                float y1 = part1 + Dh * x1;
                float z0 = zs[s][p0] + zb0;
                float z1 = zs[s][p0 + 1] + zb1;
                y0 *= z0 / (1.f + __expf(-z0));
                y1 *= z1 / (1.f + __expf(-z1));
                bf16_t* o2 = obase + (size_t)(t0 + s) * D_INNER + p0;
                o2[0] = (bf16_t)y0;
                o2[1] = (bf16_t)y1;
            }
        }
        __syncthreads();
    }
}

// ---------------------------------------------------------------------------
// act = bf16(silu(g) * u) from the fused gate|up GEMM output gu [NTOK, 11008]
// (g = cols [0,5504), u = cols [5504,11008)); writes compact [NTOK, 5504].
__global__ __launch_bounds__(256) void act_kernel(
    const bf16_t* __restrict__ gu, bf16_t* __restrict__ act, int n8)
{
    int i = blockIdx.x * 256 + threadIdx.x;
    if (i >= n8) return;
    int row = i / (INTER / 8);
    int c8  = i % (INTER / 8);
    const bf16x8* g = (const bf16x8*)(gu + (size_t)row * (2 * INTER)) + c8;
    const bf16x8* u = (const bf16x8*)(gu + (size_t)row * (2 * INTER) + INTER) + c8;
    bf16x8 gv = *g, uv = *u, r;
#pragma unroll
    for (int j = 0; j < 8; ++j) {
        float x = (float)gv[j];
        r[j] = (bf16_t)((x / (1.f + __expf(-x))) * (float)uv[j]);
    }
    ((bf16x8*)act)[i] = r;
}

// ---------------------------------------------------------------------------
extern "C" void kernel_launch(void* const* d_in, const int* in_sizes, int n_in,
                              void* d_out, int out_size, void* d_ws, size_t ws_size,
                              hipStream_t stream) {
    const float* hidden     = (const float*)d_in[0];
    const float* mask       = (const float*)d_in[1];
    const float* in_proj_w  = (const float*)d_in[2];
    const float* conv_w     = (const float*)d_in[3];
    const float* conv_b     = (const float*)d_in[4];
    const float* z_bias     = (const float*)d_in[5];
    const float* Dvec       = (const float*)d_in[6];
    const float* out_proj_w = (const float*)d_in[7];
    const float* ln1_w      = (const float*)d_in[8];
    const float* ln2_w      = (const float*)d_in[9];
    const float* gate_w     = (const float*)d_in[10];
    const float* up_w       = (const float*)d_in[11];
    const float* down_w     = (const float*)d_in[12];
    float* out = (float*)d_out;          // [4096, 2048] f32; holds h2 from step 5 on

    // workspace arena (184,942,592 B total):
    // steps 1-5 (old layout):
    //   [0, 67371008)          zxb bf16 [4096,8224]
    //   [67371008, 117702656)  convo bf16 [4096,6144]
    //   [117702656, 134479872) hn (1-2) / gated (4-5) bf16 [4096,2048]
    //   [134479872, 151257088) Schunk f32 16MB (scan)
    //   [151257088, 184942592) wbuf bf16 33.7MB (in_proj/out_proj weights)
    //                          / Sinit f32 16MB + Aprod 4KB (scan)
    // steps 6-9 (everything above dead):
    //   [0, 90177536)          guO bf16 [4096,11008] (gate|up GEMM out)
    //   [90177536, 135266304)  guW bf16 [11008,2048] weights, then actO
    //   [135266304, 152043520) h2n bf16 [4096,2048], then dwW bf16 [2048,5504]
    char* ws = (char*)d_ws;
    bf16_t* zxb    = (bf16_t*)(ws + 0);
    bf16_t* convo  = (bf16_t*)(ws + 67371008);
    bf16_t* hn     = (bf16_t*)(ws + 117702656);
    bf16_t* gated  = (bf16_t*)(ws + 117702656);
    float*  Schunk = (float*) (ws + 134479872);
    bf16_t* wbuf   = (bf16_t*)(ws + 151257088);
    float*  Sinit  = (float*) (ws + 151257088);   // scan-only, aliases wbuf
    float*  Aprod  = (float*) (ws + 168034304);
    bf16_t* guO    = (bf16_t*)(ws + 0);           // steps 7-8
    bf16_t* guW    = (bf16_t*)(ws + 90177536);    // step 7
    bf16_t* actO   = (bf16_t*)(ws + 90177536);    // step 8-9 (reuses guW)
    bf16_t* h2n    = (bf16_t*)(ws + 135266304);   // steps 6-7
    bf16_t* dwW    = (bf16_t*)(ws + 135266304);   // step 9 (reuses h2n)

    // 1. hn = rmsnorm(hidden, ln1) * mask        (bf16)
    rmsnorm_kernel<<<NTOK, 256, 0, stream>>>(hidden, ln1_w, mask, hn);
    // 2. zxb = hn @ in_proj^T  [4096, 8224]: main 8192 cols via 256^2 8-phase
    //    (grid 512 = exactly 2 full GPU rounds), A_log strip (32 cols) via
    //    the 128-tile kernel.
    cvt_kernel<<<8224, 256, 0, stream>>>(in_proj_w, wbuf, D_IN_PROJ * D_MODEL / 8);
    gemm8p<false, bf16_t><<<dim3(32, 16), 512, 0, stream>>>(
        hn, wbuf, nullptr, zxb, 8192, D_MODEL, D_IN_PROJ);
    gemm_bt<false, bf16_t><<<dim3(1, 32), 256, 0, stream>>>(
        hn, wbuf + (size_t)8192 * D_MODEL, nullptr, zxb + 8192, 32, D_MODEL, D_IN_PROJ);
    // 3. causal depthwise conv on xBC cols
    conv_kernel<<<dim3(24, 16, 2), 256, 0, stream>>>(zxb, conv_w, conv_b, convo);
    // 4. chunk-parallel SSM scan (A: chunk states, B: combine, C: outputs)
    scan_state_kernel<<<dim3(KCHUNKS, N_HEADS, BATCH), 256, 0, stream>>>(convo, zxb, Schunk, Aprod);
    scan_combine_kernel<<<1024, 256, 0, stream>>>(Schunk, Aprod, Sinit);
    scan_out_kernel<<<dim3(KCHUNKS, N_HEADS, BATCH), 256, 0, stream>>>(convo, zxb, Sinit, Dvec, z_bias, gated);
    // 5. h2 = gated @ out_proj^T + hidden        (f32, stored in d_out)
    cvt_kernel<<<2048, 256, 0, stream>>>(out_proj_w, wbuf, D_MODEL * D_INNER / 8);
    gemm_bt<true, float><<<dim3(16, 32), 256, 0, stream>>>(
        gated, wbuf, hidden, out, D_MODEL, D_INNER, D_MODEL);
    // 6. h2n = rmsnorm(h2, ln2)                  (bf16)
    rmsnorm_kernel<<<NTOK, 256, 0, stream>>>(out, ln2_w, nullptr, h2n);
    // 7. fused gate|up: guO = h2n @ [gate_w; up_w]^T  [4096, 11008]
    cvt_kernel<<<5504, 256, 0, stream>>>(gate_w, guW, INTER * D_MODEL / 8);
    cvt_kernel<<<5504, 256, 0, stream>>>(up_w, guW + (size_t)INTER * D_MODEL, INTER * D_MODEL / 8);
    gemm8p<false, bf16_t><<<dim3(43, 16), 512, 0, stream>>>(
        h2n, guW, nullptr, guO, 2 * INTER, D_MODEL, 2 * INTER);
    // 8. actO = silu(g)*u                        (compact [4096, 5504])
    act_kernel<<<11008, 256, 0, stream>>>(guO, actO, NTOK * INTER / 8);
    // 9. out = actO @ down_w^T + h2              (f32, in-place residual)
    cvt_kernel<<<5504, 256, 0, stream>>>(down_w, dwW, D_MODEL * INTER / 8);
    gemm_bt<true, float><<<dim3(16, 32), 256, 0, stream>>>(
        actO, dwW, out, out, D_MODEL, INTER, D_MODEL);
}

// Round 4
// 1039.516 us; speedup vs baseline: 1.1312x; 1.0016x over previous
//
#include <hip/hip_runtime.h>
#include <math.h>

typedef __bf16 bf16_t;
typedef __attribute__((ext_vector_type(8))) __bf16 bf16x8;
typedef __attribute__((ext_vector_type(4))) float f32x4;

#define D_MODEL   2048
#define L_SEQ     2048
#define BATCH     2
#define NTOK      4096      // BATCH * L_SEQ
#define N_HEADS   32
#define D_STATE   64
#define HEADDIM   64
#define D_INNER   2048
#define CONV_DIM  6144      // d_inner + 2*H*N
#define D_IN_PROJ 8224      // 2*d_inner + 2*H*N + H
#define INTER     5504
#define QCHUNK    128       // scan chunk length
#define KCHUNKS   16        // L_SEQ / QCHUNK

// ---------------------------------------------------------------------------
// async global->LDS (width 16B). HW dest = wave-uniform base + lane*16; our
// LDS layouts are linear in tid*16 so per-lane pointers match HW placement.
__device__ __forceinline__ void gld_lds16(const void* g, void* l) {
    __builtin_amdgcn_global_load_lds(
        (const __attribute__((address_space(1))) unsigned int*)g,
        (__attribute__((address_space(3))) unsigned int*)l, 16, 0, 0);
}

// bijective XCD-chunk swizzle (m204): orig -> wg such that each XCD gets a
// contiguous wg-range. Caller maps wg -> (m,n) M-FAST so each XCD owns a
// narrow n-range (W-slice L2-resident) and sweeps all m within it.
__device__ __forceinline__ int xcd_swizzle(int orig, int nwg) {
    int qx = nwg >> 3, rx = nwg & 7;
    int xcd = orig & 7, l8 = orig >> 3;
    return (xcd < rx ? xcd * (qx + 1) : rx * (qx + 1) + (xcd - rx) * qx) + l8;
}

// ---------------------------------------------------------------------------
// f32 -> bf16 convert, 8 elems/thread
__global__ __launch_bounds__(256) void cvt_kernel(
    const float* __restrict__ s, bf16_t* __restrict__ d, int n8)
{
    int i = blockIdx.x * 256 + threadIdx.x;
    if (i >= n8) return;
    const float4* s4 = (const float4*)s;
    float4 a = s4[2 * i], b = s4[2 * i + 1];
    bf16x8 r;
    r[0] = (bf16_t)a.x; r[1] = (bf16_t)a.y; r[2] = (bf16_t)a.z; r[3] = (bf16_t)a.w;
    r[4] = (bf16_t)b.x; r[5] = (bf16_t)b.y; r[6] = (bf16_t)b.z; r[7] = (bf16_t)b.w;
    ((bf16x8*)d)[i] = r;
}

// ---------------------------------------------------------------------------
// RMSNorm: one block per token row; f32 in, bf16 out.
__global__ __launch_bounds__(256) void rmsnorm_kernel(
    const float* __restrict__ x, const float* __restrict__ w,
    const float* __restrict__ mask, bf16_t* __restrict__ out)
{
    __shared__ float red[4];
    __shared__ float sinv;
    int row = blockIdx.x;
    const float* xr = x + (size_t)row * D_MODEL;
    float xv[8];
    float ss = 0.f;
#pragma unroll
    for (int i = 0; i < 8; ++i) {
        float v = xr[threadIdx.x + 256 * i];
        xv[i] = v;
        ss += v * v;
    }
    for (int off = 32; off >= 1; off >>= 1) ss += __shfl_down(ss, off, 64);
    int lane = threadIdx.x & 63, wv = threadIdx.x >> 6;
    if (lane == 0) red[wv] = ss;
    __syncthreads();
    if (threadIdx.x == 0) {
        float t = red[0] + red[1] + red[2] + red[3];
        sinv = rsqrtf(t / (float)D_MODEL + 1e-6f);
    }
    __syncthreads();
    float s = sinv;
    float m = mask ? mask[row] : 1.f;
    bf16_t* orow = out + (size_t)row * D_MODEL;
#pragma unroll
    for (int i = 0; i < 8; ++i) {
        int c = threadIdx.x + 256 * i;
        orow[c] = (bf16_t)(xv[i] * s * w[c] * m);
    }
}

// ---------------------------------------------------------------------------
// GEMM (m97 structure, 128x128 tile, BK=32): O[M,N] = X[M,K] @ W[N,K]^T
// (+ optional f32 residual R). Kept for small-N GEMMs (out_proj, down,
// in_proj A_log strip) where the 256^2 kernel would underfill the GPU.
// v3: XCD column-chunk swizzle (each XCD owns a narrow n-range -> its
// 128-col W-slice stays L2-resident across the m-sweep).
template <bool RES, typename OT>
__global__ __launch_bounds__(256) void gemm_bt(
    const bf16_t* __restrict__ X, const bf16_t* __restrict__ W,
    const float* __restrict__ R, OT* __restrict__ O,
    int N, int K, int ldo)
{
    __shared__ __attribute__((aligned(16))) bf16_t As[128 * 32];
    __shared__ __attribute__((aligned(16))) bf16_t Bs[128 * 32];

    int tid = threadIdx.x;
    int ny = gridDim.y;
    int wg = xcd_swizzle(blockIdx.x + gridDim.x * blockIdx.y, gridDim.x * ny);
    int m0 = (wg % ny) * 128;           // m-fast within an XCD chunk
    int n0 = (wg / ny) * 128;

    f32x4 acc[4][4] = {};

    int lane = tid & 63;
    int wv = tid >> 6;
    int wm = (wv >> 1) * 64, wn = (wv & 1) * 64;
    int lm = lane & 15, lq = lane >> 4;

    int srow = tid >> 2;            // 0..63
    int scol = (tid & 3) * 8;       // element col 0/8/16/24
    const bf16_t* Xp0 = X + (size_t)(m0 + srow) * K + scol;
    const bf16_t* Xp1 = X + (size_t)(m0 + 64 + srow) * K + scol;
    int wr0 = n0 + srow;      if (wr0 > N - 1) wr0 = N - 1;  // clamp OOB rows
    int wr1 = n0 + 64 + srow; if (wr1 > N - 1) wr1 = N - 1;
    const bf16_t* Wp0 = W + (size_t)wr0 * K + scol;
    const bf16_t* Wp1 = W + (size_t)wr1 * K + scol;
    bf16_t* lA0 = &As[tid * 8];
    bf16_t* lA1 = &As[2048 + tid * 8];
    bf16_t* lB0 = &Bs[tid * 8];
    bf16_t* lB1 = &Bs[2048 + tid * 8];

    for (int k0 = 0; k0 < K; k0 += 32) {
        __syncthreads();                 // prev iter's LDS reads done
        gld_lds16(Xp0 + k0, lA0);
        gld_lds16(Xp1 + k0, lA1);
        gld_lds16(Wp0 + k0, lB0);
        gld_lds16(Wp1 + k0, lB1);
        __syncthreads();                 // compiler drains vmcnt before barrier

        bf16x8 a[4], b[4];
#pragma unroll
        for (int i = 0; i < 4; ++i)
            a[i] = *(const bf16x8*)&As[(wm + i * 16 + lm) * 32 + lq * 8];
#pragma unroll
        for (int i = 0; i < 4; ++i)
            b[i] = *(const bf16x8*)&Bs[(wn + i * 16 + lm) * 32 + lq * 8];
#pragma unroll
        for (int mi = 0; mi < 4; ++mi)
#pragma unroll
            for (int ni = 0; ni < 4; ++ni)
                acc[mi][ni] = __builtin_amdgcn_mfma_f32_16x16x32_bf16(
                    a[mi], b[ni], acc[mi][ni], 0, 0, 0);
    }

    // epilogue: C/D layout col=lane&15, row=(lane>>4)*4+reg  [verified m89/m91]
#pragma unroll
    for (int mi = 0; mi < 4; ++mi)
#pragma unroll
        for (int ni = 0; ni < 4; ++ni) {
            int n = n0 + wn + ni * 16 + lm;
            if (n >= N) continue;
            int mbase = m0 + wm + mi * 16 + lq * 4;
#pragma unroll
            for (int r = 0; r < 4; ++r) {
                size_t off = (size_t)(mbase + r) * ldo + n;
                float v = acc[mi][ni][r];
                if (RES) v += R[off];
                O[off] = (OT)v;
            }
        }
}

// ---------------------------------------------------------------------------
// 256x256 8-phase GEMM (T1 XCD swizzle + T2 st_16x32 LDS swizzle + T3/T4
// counted-vmcnt 8-phase + T5 setprio):  O[M,N] = X[M,K] @ W[N,K]^T.
// Requirements: M == gridDim.y*256, K % 128 == 0, N <= gridDim.x*256
// (OOB W rows clamped, OOB cols not stored). 512 threads = 8 waves (2Mx4N),
// per-wave 128x64 output (acc[8][4]); LDS 128 KiB = 2 dbuf slots of
// {A: 2x(128x64), B: 2x(128x64)} bf16.
//
// v2 (spill fix): fragment reads are spread per-phase (12/4/8/0 per K-tile),
// so live frags = a[4][2]+b[4][2] = 64 VGPR.
// v3 (L2 locality): m-fast wg->(m,n) map. v2's n-fast map made each XCD
// stream the ENTIRE W panel per m-row (FETCH_SIZE = 8x unique bytes, 368MB);
// m-fast gives each XCD a ~4-6MB W-slice that stays L2-resident.
//
// LDS layout per 16 KiB half-tile: 16-row x 32-col subtiles stored
// contiguously (1024 B), XOR-swizzled; global_load_lds writes linearly
// (tid*16); swizzle applied by pre-permuting the per-lane GLOBAL source
// address (both-sides rule, m104/m201). Region map per 64 KiB slot:
//   A-h0 [0,16K) rows 0..127 | A-h1 [16K,32K) rows 128..255
//   B-h0 [32K,48K) W-rows 0..127 | B-h1 [48K,64K) W-rows 128..255
//
// Read schedule per K-tile (slot SO), one quadrant of acc per phase:
//   Pa: read a-lo (rows +0..63, 8x b128) + b01 (4x) ; MFMA acc[0..3][0..1]
//   Pb: read b23 (4x)                               ; MFMA acc[0..3][2..3]
//   Pc: read a-hi (rows +64..127, 8x, overwrite a)  ; MFMA acc[4..7][0..1]
//   Pd: no reads                                    ; MFMA acc[4..7][2..3]
// Stage stream (1 half-tile = 2 loads/wave per phase):
//   P1:(2t+1).Ah0 P2:(2t+1).Ah1 P3:(2t+2).Bh0 P4:(2t+2).Bh1
//   P5:(2t+2).Ah0 P6:(2t+2).Ah1 P7:(2t+3).Bh0 P8:(2t+3).Bh1
// Landing guards: vmcnt(4) at P4 (slot1 tile fully landed) and at P8
// (slot0 landed). Last iteration: vmcnt(0) at P4. Prologue: tile0 all 4
// halves + tile1 B-halves (6 stages), vmcnt(4) = tile0 landed.

#define G8_BARRIER() do { asm volatile("" ::: "memory"); \
    __builtin_amdgcn_s_barrier(); \
    asm volatile("" ::: "memory"); } while (0)
#define G8_LGKM0() do { asm volatile("s_waitcnt lgkmcnt(0)" ::: "memory"); \
    __builtin_amdgcn_sched_barrier(0); } while (0)
#define G8_VMCNT(n) asm volatile("s_waitcnt vmcnt(" #n ")" ::: "memory")

template <int W>
__device__ __forceinline__ void g8_stage(
    int tile, int NT, const bf16_t* pA, size_t hK64,
    const bf16_t* pB0, const bf16_t* pB1, const bf16_t* pB2, const bf16_t* pB3,
    unsigned dbase, bf16_t* lds)
{
    if (tile >= NT) return;                           // uniform tail guard
    unsigned so = ((tile & 1) ? 65536u : 0u) + (unsigned)W * 16384u;
    size_t goff = (size_t)tile * 64;                  // K-tile column offset
    const bf16_t *g0, *g1;
    if constexpr (W == 0)      { g0 = pA;              g1 = pA + hK64; }
    else if constexpr (W == 1) { g0 = pA + 2 * hK64;   g1 = pA + 3 * hK64; }
    else if constexpr (W == 2) { g0 = pB0;             g1 = pB1; }
    else                       { g0 = pB2;             g1 = pB3; }
    gld_lds16(g0 + goff, (char*)lds + (so + dbase));
    gld_lds16(g1 + goff, (char*)lds + (so + 8192u + dbase));
}

template <bool RES, typename OT>
__global__ __launch_bounds__(512, 2) void gemm8p(
    const bf16_t* __restrict__ X, const bf16_t* __restrict__ W,
    const float* __restrict__ R, OT* __restrict__ O,
    int N, int K, int ldo)
{
    __shared__ __attribute__((aligned(1024))) bf16_t lds[65536];   // 128 KiB

    const int tid  = threadIdx.x;
    const int lane = tid & 63;
    const int wid  = tid >> 6;
    const int wr   = wid >> 2;          // wave row 0..1  (128 M-rows each)
    const int wc   = wid & 3;           // wave col 0..3  (64 N-cols each)

    // T1: bijective XCD chunking + m-fast map (XCD owns a narrow n-range)
    int ny = gridDim.y;
    int wg = xcd_swizzle(blockIdx.x + gridDim.x * blockIdx.y, gridDim.x * ny);
    int m0 = (wg % ny) * 256;
    int n0 = (wg / ny) * 256;

    const int NT    = K >> 6;           // K-tiles (BK=64); NT even (K%128==0)
    const int niter = NT >> 1;

    // ---- stage addressing: thread tid's 16 B lands at linear LDS byte
    // p = i*8192 + tid*16 of a half-tile region; the element that belongs
    // there under the read-side swizzle is (lrow [+64 for i=1], lcol):
    int lrow = ((tid >> 7) << 4) + ((tid >> 2) & 15);
    int cb   = (tid & 3) * 16;
    int cblg = cb ^ (((tid >> 2) & 8) ? 32 : 0);      // inverse == forward (XOR)
    int lcol = (((tid >> 6) & 1) << 5) + (cblg >> 1);
    const size_t hK64 = (size_t)K << 6;               // 64 rows worth of K
    const bf16_t* pA = X + (size_t)(m0 + lrow) * K + lcol;
    const bf16_t* pB[4];
#pragma unroll
    for (int hi = 0; hi < 4; ++hi) {                  // hi = h*2 + i
        int rw = n0 + (hi >> 1) * 128 + (hi & 1) * 64 + lrow;
        if (rw > N - 1) rw = N - 1;                   // clamp OOB W rows
        pB[hi] = W + (size_t)rw * K + lcol;
    }
    const unsigned dbase = (unsigned)tid * 16u;

    // ---- LDS read bases (swizzled): frag (idx, ks) at +(idx*2+ks)*1024
    unsigned c2s = ((unsigned)(lane >> 4) << 4) ^ ((lane & 8) ? 32u : 0u);
    unsigned rdA = (unsigned)(wr * 16384 + (lane & 15) * 64) + c2s;
    unsigned rdB = 32768u + (unsigned)((wc >> 1) * 16384 + (wc & 1) * 8192
                                       + (lane & 15) * 64) + c2s;

    f32x4 acc[8][4] = {};
    bf16x8 a[4][2], b[4][2];

#define G8_STG(W_, TILE) g8_stage<W_>((TILE), NT, pA, hK64, \
    pB[0], pB[1], pB[2], pB[3], dbase, lds)
#define G8_LDA(SO, HI) do { \
    const char* pa_ = (const char*)lds + (SO) + rdA + (HI) * 8192; \
    _Pragma("unroll") for (int mi = 0; mi < 4; ++mi) { \
        a[mi][0] = *(const bf16x8*)(pa_ + mi * 2048); \
        a[mi][1] = *(const bf16x8*)(pa_ + mi * 2048 + 1024); } \
} while (0)
#define G8_LDB(SO, NI0) do { \
    const char* pb_ = (const char*)lds + (SO) + rdB + (NI0) * 2048; \
    _Pragma("unroll") for (int nj = 0; nj < 2; ++nj) { \
        b[(NI0) + nj][0] = *(const bf16x8*)(pb_ + nj * 2048); \
        b[(NI0) + nj][1] = *(const bf16x8*)(pb_ + nj * 2048 + 1024); } \
} while (0)
#define G8_MFMAQ(MI0, NI0) do { \
    __builtin_amdgcn_s_setprio(1); \
    _Pragma("unroll") for (int mi = 0; mi < 4; ++mi) \
    _Pragma("unroll") for (int ni = 0; ni < 2; ++ni) \
    _Pragma("unroll") for (int ks = 0; ks < 2; ++ks) \
        acc[(MI0) + mi][(NI0) + ni] = __builtin_amdgcn_mfma_f32_16x16x32_bf16( \
            a[mi][ks], b[(NI0) + ni][ks], acc[(MI0) + mi][(NI0) + ni], 0, 0, 0); \
    __builtin_amdgcn_s_setprio(0); \
} while (0)

    // ---- prologue: tile0 all halves + tile1 B-halves
    G8_STG(2, 0); G8_STG(3, 0); G8_STG(0, 0); G8_STG(1, 0);
    G8_STG(2, 1); G8_STG(3, 1);
    G8_VMCNT(4);            // tile0's 8 loads landed
    G8_BARRIER();

#pragma unroll 1
    for (int t = 0; t < niter; ++t) {
        const int t2 = 2 * t;
        // ---- P1 (slot0 = tile 2t): a-lo + b01
        G8_STG(0, t2 + 1);
        G8_LDA(0u, 0); G8_LDB(0u, 0);
        G8_BARRIER(); G8_LGKM0();
        G8_MFMAQ(0, 0);
        G8_BARRIER();
        // ---- P2: b23
        G8_STG(1, t2 + 1);
        G8_LDB(0u, 2);
        G8_BARRIER(); G8_LGKM0();
        G8_MFMAQ(0, 2);
        G8_BARRIER();
        // ---- P3: a-hi
        G8_STG(2, t2 + 2);
        G8_LDA(0u, 1);
        G8_BARRIER(); G8_LGKM0();
        G8_MFMAQ(4, 0);
        G8_BARRIER();
        // ---- P4
        G8_STG(3, t2 + 2);
        if (t == niter - 1) { G8_VMCNT(0); } else { G8_VMCNT(4); }
        G8_BARRIER();
        G8_MFMAQ(4, 2);
        G8_BARRIER();
        // ---- P5 (slot1 = tile 2t+1): a-lo + b01
        G8_STG(0, t2 + 2);
        G8_LDA(65536u, 0); G8_LDB(65536u, 0);
        G8_BARRIER(); G8_LGKM0();
        G8_MFMAQ(0, 0);
        G8_BARRIER();
        // ---- P6: b23
        G8_STG(1, t2 + 2);
        G8_LDB(65536u, 2);
        G8_BARRIER(); G8_LGKM0();
        G8_MFMAQ(0, 2);
        G8_BARRIER();
        // ---- P7: a-hi
        G8_STG(2, t2 + 3);
        G8_LDA(65536u, 1);
        G8_BARRIER(); G8_LGKM0();
        G8_MFMAQ(4, 0);
        G8_BARRIER();
        // ---- P8
        G8_STG(3, t2 + 3);
        G8_VMCNT(4);
        G8_BARRIER();
        G8_MFMAQ(4, 2);
        G8_BARRIER();
    }

#undef G8_STG
#undef G8_LDA
#undef G8_LDB
#undef G8_MFMAQ

    // ---- epilogue: C/D layout col=lane&15, row=(lane>>4)*4+reg
#pragma unroll
    for (int mi = 0; mi < 8; ++mi)
#pragma unroll
        for (int ni = 0; ni < 4; ++ni) {
            int n = n0 + wc * 64 + ni * 16 + (lane & 15);
            if (n >= N) continue;
            int mbase = m0 + wr * 128 + mi * 16 + (lane >> 4) * 4;
#pragma unroll
            for (int r = 0; r < 4; ++r) {
                size_t off = (size_t)(mbase + r) * ldo + n;
                float v = acc[mi][ni][r];
                if (RES) v += R[off];
                O[off] = (OT)v;
            }
        }
}

// ---------------------------------------------------------------------------
// causal depthwise conv1d (taps=4): rolling registers per channel.
__global__ __launch_bounds__(256) void conv_kernel(
    const bf16_t* __restrict__ zx, const float* __restrict__ cw,
    const float* __restrict__ cb, bf16_t* __restrict__ out)
{
    int c = blockIdx.x * 256 + threadIdx.x;   // 0..6143
    int l0 = blockIdx.y * 128;
    int b = blockIdx.z;
    float w0 = cw[c * 4 + 0], w1 = cw[c * 4 + 1];
    float w2 = cw[c * 4 + 2], w3 = cw[c * 4 + 3];
    float bias = cb[c];
    const bf16_t* src = zx + (size_t)b * L_SEQ * D_IN_PROJ + 2048 + c;
    bf16_t* dst = out + (size_t)b * L_SEQ * CONV_DIM + c;
    float xm3 = (l0 >= 3) ? (float)src[(size_t)(l0 - 3) * D_IN_PROJ] : 0.f;
    float xm2 = (l0 >= 2) ? (float)src[(size_t)(l0 - 2) * D_IN_PROJ] : 0.f;
    float xm1 = (l0 >= 1) ? (float)src[(size_t)(l0 - 1) * D_IN_PROJ] : 0.f;
    for (int l = l0; l < l0 + 128; ++l) {
        float xc = (float)src[(size_t)l * D_IN_PROJ];
        float r = bias + xm3 * w0 + xm2 * w1 + xm1 * w2 + xc * w3;
        dst[(size_t)l * CONV_DIM] = (bf16_t)r;
        xm3 = xm2; xm2 = xm1; xm1 = xc;
    }
}

// ---------------------------------------------------------------------------
// SSM scan pass A: per-(b,h,chunk) state-only scan over Q=128 steps.
__global__ __launch_bounds__(256) void scan_state_kernel(
    const bf16_t* __restrict__ conv, const bf16_t* __restrict__ zx,
    float* __restrict__ Schunk, float* __restrict__ Aprod)
{
    const int SS = 32;
    __shared__ __attribute__((aligned(16))) float xs[SS][64];
    __shared__ __attribute__((aligned(16))) float bs[SS][64];
    __shared__ float as_[SS];

    int k = blockIdx.x, h = blockIdx.y, b = blockIdx.z;
    int tid = threadIdx.x, lane = tid & 63, wv = tid >> 6;
    int pt = tid >> 3, nt = tid & 7;
    int p0 = pt * 2, n0 = nt * 8;

    float st0[8] = {0, 0, 0, 0, 0, 0, 0, 0};
    float st1[8] = {0, 0, 0, 0, 0, 0, 0, 0};
    float aprod = 1.f;

    const bf16_t* cbase = conv + (size_t)b * L_SEQ * CONV_DIM + h * 64;
    const bf16_t* abase = zx + (size_t)b * L_SEQ * D_IN_PROJ + 8192 + h;

    int tstart = k * QCHUNK;
    for (int t0 = tstart; t0 < tstart + QCHUNK; t0 += SS) {
        int soff = (wv >> 1) * 16;
        for (int s = 0; s < 16; ++s) {
            size_t row = (size_t)(t0 + soff + s);
            if ((wv & 1) == 0) xs[soff + s][lane] = (float)cbase[row * CONV_DIM + lane];
            else               bs[soff + s][lane] = (float)cbase[row * CONV_DIM + 2048 + lane];
        }
        if (tid < SS) {
            float v = (float)abase[(size_t)(t0 + tid) * D_IN_PROJ];
            as_[tid] = 1.f / (1.f + __expf(v));     // exp(-softplus(v))
        }
        __syncthreads();
        for (int s = 0; s < SS; ++s) {
            float a = as_[s];
            float x0 = xs[s][p0], x1 = xs[s][p0 + 1];
            aprod *= a;
#pragma unroll
            for (int j = 0; j < 8; ++j) {
                float Bv = bs[s][n0 + j];
                st0[j] = a * st0[j] + x0 * Bv;
                st1[j] = a * st1[j] + x1 * Bv;
            }
        }
        __syncthreads();
    }
    size_t base = (((size_t)(b * N_HEADS + h)) * KCHUNKS + k) * 4096;
    float4* d0 = (float4*)&Schunk[base + p0 * 64 + n0];
    d0[0] = make_float4(st0[0], st0[1], st0[2], st0[3]);
    d0[1] = make_float4(st0[4], st0[5], st0[6], st0[7]);
    float4* d1 = (float4*)&Schunk[base + (p0 + 1) * 64 + n0];
    d1[0] = make_float4(st1[0], st1[1], st1[2], st1[3]);
    d1[1] = make_float4(st1[4], st1[5], st1[6], st1[7]);
    if (tid == 0) Aprod[(b * N_HEADS + h) * KCHUNKS + k] = aprod;
}

// ---------------------------------------------------------------------------
// SSM scan pass B: elementwise inter-chunk combine.
__global__ __launch_bounds__(256) void scan_combine_kernel(
    const float* __restrict__ Schunk, const float* __restrict__ Aprod,
    float* __restrict__ Sinit)
{
    int bh = blockIdx.x >> 4;
    int e = (blockIdx.x & 15) * 256 + threadIdx.x;   // 0..4095
    size_t base = (size_t)bh * KCHUNKS * 4096 + e;
    float S = 0.f;
    for (int k = 0; k < KCHUNKS; ++k) {
        Sinit[base + (size_t)k * 4096] = S;
        float ap = Aprod[bh * KCHUNKS + k];
        S = ap * S + Schunk[base + (size_t)k * 4096];
    }
}

// ---------------------------------------------------------------------------
// SSM scan pass C: per-(b,h,chunk) output scan from Sinit. Fuses y += D*x and
// gated = y*silu(z+zb); writes bf16 [NTOK, 2048]. grid (K,H,B).
__global__ __launch_bounds__(256) void scan_out_kernel(
    const bf16_t* __restrict__ conv, const bf16_t* __restrict__ zx,
    const float* __restrict__ Sinit, const float* __restrict__ Dp,
    const float* __restrict__ zb, bf16_t* __restrict__ gated)
{
    const int S = 16;
    __shared__ __attribute__((aligned(16))) float xs[S][64];
    __shared__ __attribute__((aligned(16))) float bs[S][64];
    __shared__ __attribute__((aligned(16))) float cs[S][64];
    __shared__ __attribute__((aligned(16))) float zs[S][64];
    __shared__ float as_[S];

    int k = blockIdx.x, h = blockIdx.y, b = blockIdx.z;
    int tid = threadIdx.x;
    int lane = tid & 63, wv = tid >> 6;
    int pt = tid >> 3, nt = tid & 7;
    int p0 = pt * 2, n0 = nt * 8;

    size_t sbase = (((size_t)(b * N_HEADS + h)) * KCHUNKS + k) * 4096;
    float4 v00 = *(const float4*)&Sinit[sbase + p0 * 64 + n0];
    float4 v01 = *(const float4*)&Sinit[sbase + p0 * 64 + n0 + 4];
    float4 v10 = *(const float4*)&Sinit[sbase + (p0 + 1) * 64 + n0];
    float4 v11 = *(const float4*)&Sinit[sbase + (p0 + 1) * 64 + n0 + 4];
    float st0[8] = {v00.x, v00.y, v00.z, v00.w, v01.x, v01.y, v01.z, v01.w};
    float st1[8] = {v10.x, v10.y, v10.z, v10.w, v11.x, v11.y, v11.z, v11.w};

    float Dh  = Dp[h];
    float zb0 = zb[h * 64 + p0];
    float zb1 = zb[h * 64 + p0 + 1];

    const bf16_t* cbase = conv + (size_t)b * L_SEQ * CONV_DIM + h * 64;
    const bf16_t* zbase = zx + (size_t)b * L_SEQ * D_IN_PROJ + h * 64;
    const bf16_t* abase = zx + (size_t)b * L_SEQ * D_IN_PROJ + 8192 + h;
    bf16_t* obase = gated + (size_t)b * L_SEQ * D_INNER + h * 64;

    int tstart = k * QCHUNK;
    for (int t0 = tstart; t0 < tstart + QCHUNK; t0 += S) {
        for (int s = 0; s < S; ++s) {
            size_t row = (size_t)(t0 + s);
            if (wv == 0)      xs[s][lane] = (float)cbase[row * CONV_DIM + lane];
            else if (wv == 1) bs[s][lane] = (float)cbase[row * CONV_DIM + 2048 + lane];
            else if (wv == 2) cs[s][lane] = (float)cbase[row * CONV_DIM + 4096 + lane];
            else              zs[s][lane] = (float)zbase[row * D_IN_PROJ + lane];
        }
        if (tid < S) {
            float v = (float)abase[(size_t)(t0 + tid) * D_IN_PROJ];
            as_[tid] = 1.f / (1.f + __expf(v));     // exp(-softplus(v))
        }
        __syncthreads();

        for (int s = 0; s < S; ++s) {
            float a = as_[s];
            float x0 = xs[s][p0], x1 = xs[s][p0 + 1];
            float part0 = 0.f, part1 = 0.f;
#pragma unroll
            for (int j = 0; j < 8; ++j) {
                float Bv = bs[s][n0 + j];
                float Cv = cs[s][n0 + j];
                st0[j] = a * st0[j] + x0 * Bv;
                st1[j] = a * st1[j] + x1 * Bv;
                part0 += st0[j] * Cv;
                part1 += st1[j] * Cv;
            }
            for (int o = 1; o < 8; o <<= 1) {
                part0 += __shfl_xor(part0, o, 64);
                part1 += __shfl_xor(part1, o, 64);
            }
            if (nt == 0) {
                float y0 = part0 + Dh * x0;
                float y1 = part1 + Dh * x1;
                float z0 = zs[s][p0] + zb0;
                float z1 = zs[s][p0 + 1] + zb1;
                y0 *= z0 / (1.f + __expf(-z0));
                y1 *= z1 / (1.f + __expf(-z1));
                bf16_t* o2 = obase + (size_t)(t0 + s) * D_INNER + p0;
                o2[0] = (bf16_t)y0;
                o2[1] = (bf16_t)y1;
            }
        }
        __syncthreads();
    }
}

// ---------------------------------------------------------------------------
// act = bf16(silu(g) * u) from the fused gate|up GEMM output gu [NTOK, 11008]
// (g = cols [0,5504), u = cols [5504,11008)); writes compact [NTOK, 5504].
__global__ __launch_bounds__(256) void act_kernel(
    const bf16_t* __restrict__ gu, bf16_t* __restrict__ act, int n8)
{
    int i = blockIdx.x * 256 + threadIdx.x;
    if (i >= n8) return;
    int row = i / (INTER / 8);
    int c8  = i % (INTER / 8);
    const bf16x8* g = (const bf16x8*)(gu + (size_t)row * (2 * INTER)) + c8;
    const bf16x8* u = (const bf16x8*)(gu + (size_t)row * (2 * INTER) + INTER) + c8;
    bf16x8 gv = *g, uv = *u, r;
#pragma unroll
    for (int j = 0; j < 8; ++j) {
        float x = (float)gv[j];
        r[j] = (bf16_t)((x / (1.f + __expf(-x))) * (float)uv[j]);
    }
    ((bf16x8*)act)[i] = r;
}

// ---------------------------------------------------------------------------
extern "C" void kernel_launch(void* const* d_in, const int* in_sizes, int n_in,
                              void* d_out, int out_size, void* d_ws, size_t ws_size,
                              hipStream_t stream) {
    const float* hidden     = (const float*)d_in[0];
    const float* mask       = (const float*)d_in[1];
    const float* in_proj_w  = (const float*)d_in[2];
    const float* conv_w     = (const float*)d_in[3];
    const float* conv_b     = (const float*)d_in[4];
    const float* z_bias     = (const float*)d_in[5];
    const float* Dvec       = (const float*)d_in[6];
    const float* out_proj_w = (const float*)d_in[7];
    const float* ln1_w      = (const float*)d_in[8];
    const float* ln2_w      = (const float*)d_in[9];
    const float* gate_w     = (const float*)d_in[10];
    const float* up_w       = (const float*)d_in[11];
    const float* down_w     = (const float*)d_in[12];
    float* out = (float*)d_out;          // [4096, 2048] f32; holds h2 from step 5 on

    // workspace arena (184,942,592 B total):
    // steps 1-5 (old layout):
    //   [0, 67371008)          zxb bf16 [4096,8224]
    //   [67371008, 117702656)  convo bf16 [4096,6144]
    //   [117702656, 134479872) hn (1-2) / gated (4-5) bf16 [4096,2048]
    //   [134479872, 151257088) Schunk f32 16MB (scan)
    //   [151257088, 184942592) wbuf bf16 33.7MB (in_proj/out_proj weights)
    //                          / Sinit f32 16MB + Aprod 4KB (scan)
    // steps 6-9 (everything above dead):
    //   [0, 90177536)          guO bf16 [4096,11008] (gate|up GEMM out)
    //   [90177536, 135266304)  guW bf16 [11008,2048] weights, then actO
    //   [135266304, 152043520) h2n bf16 [4096,2048], then dwW bf16 [2048,5504]
    char* ws = (char*)d_ws;
    bf16_t* zxb    = (bf16_t*)(ws + 0);
    bf16_t* convo  = (bf16_t*)(ws + 67371008);
    bf16_t* hn     = (bf16_t*)(ws + 117702656);
    bf16_t* gated  = (bf16_t*)(ws + 117702656);
    float*  Schunk = (float*) (ws + 134479872);
    bf16_t* wbuf   = (bf16_t*)(ws + 151257088);
    float*  Sinit  = (float*) (ws + 151257088);   // scan-only, aliases wbuf
    float*  Aprod  = (float*) (ws + 168034304);
    bf16_t* guO    = (bf16_t*)(ws + 0);           // steps 7-8
    bf16_t* guW    = (bf16_t*)(ws + 90177536);    // step 7
    bf16_t* actO   = (bf16_t*)(ws + 90177536);    // step 8-9 (reuses guW)
    bf16_t* h2n    = (bf16_t*)(ws + 135266304);   // steps 6-7
    bf16_t* dwW    = (bf16_t*)(ws + 135266304);   // step 9 (reuses h2n)

    // 1. hn = rmsnorm(hidden, ln1) * mask        (bf16)
    rmsnorm_kernel<<<NTOK, 256, 0, stream>>>(hidden, ln1_w, mask, hn);
    // 2. zxb = hn @ in_proj^T  [4096, 8224]: main 8192 cols via 256^2 8-phase
    //    (grid 512 = exactly 2 full GPU rounds), A_log strip (32 cols) via
    //    the 128-tile kernel.
    cvt_kernel<<<8224, 256, 0, stream>>>(in_proj_w, wbuf, D_IN_PROJ * D_MODEL / 8);
    gemm8p<false, bf16_t><<<dim3(32, 16), 512, 0, stream>>>(
        hn, wbuf, nullptr, zxb, 8192, D_MODEL, D_IN_PROJ);
    gemm_bt<false, bf16_t><<<dim3(1, 32), 256, 0, stream>>>(
        hn, wbuf + (size_t)8192 * D_MODEL, nullptr, zxb + 8192, 32, D_MODEL, D_IN_PROJ);
    // 3. causal depthwise conv on xBC cols
    conv_kernel<<<dim3(24, 16, 2), 256, 0, stream>>>(zxb, conv_w, conv_b, convo);
    // 4. chunk-parallel SSM scan (A: chunk states, B: combine, C: outputs)
    scan_state_kernel<<<dim3(KCHUNKS, N_HEADS, BATCH), 256, 0, stream>>>(convo, zxb, Schunk, Aprod);
    scan_combine_kernel<<<1024, 256, 0, stream>>>(Schunk, Aprod, Sinit);
    scan_out_kernel<<<dim3(KCHUNKS, N_HEADS, BATCH), 256, 0, stream>>>(convo, zxb, Sinit, Dvec, z_bias, gated);
    // 5. h2 = gated @ out_proj^T + hidden        (f32, stored in d_out)
    cvt_kernel<<<2048, 256, 0, stream>>>(out_proj_w, wbuf, D_MODEL * D_INNER / 8);
    gemm_bt<true, float><<<dim3(16, 32), 256, 0, stream>>>(
        gated, wbuf, hidden, out, D_MODEL, D_INNER, D_MODEL);
    // 6. h2n = rmsnorm(h2, ln2)                  (bf16)
    rmsnorm_kernel<<<NTOK, 256, 0, stream>>>(out, ln2_w, nullptr, h2n);
    // 7. fused gate|up: guO = h2n @ [gate_w; up_w]^T  [4096, 11008]
    cvt_kernel<<<5504, 256, 0, stream>>>(gate_w, guW, INTER * D_MODEL / 8);
    cvt_kernel<<<5504, 256, 0, stream>>>(up_w, guW + (size_t)INTER * D_MODEL, INTER * D_MODEL / 8);
    gemm8p<false, bf16_t><<<dim3(43, 16), 512, 0, stream>>>(
        h2n, guW, nullptr, guO, 2 * INTER, D_MODEL, 2 * INTER);
    // 8. actO = silu(g)*u                        (compact [4096, 5504])
    act_kernel<<<11008, 256, 0, stream>>>(guO, actO, NTOK * INTER / 8);
    // 9. out = actO @ down_w^T + h2              (f32, in-place residual)
    cvt_kernel<<<5504, 256, 0, stream>>>(down_w, dwW, D_MODEL * INTER / 8);
    gemm_bt<true, float><<<dim3(16, 32), 256, 0, stream>>>(
        actO, dwW, out, out, D_MODEL, INTER, D_MODEL);
}